// Round 5
// baseline (592.639 us; speedup 1.0000x reference)
//
#include <hip/hip_runtime.h>
#include <hip/hip_bf16.h>
#include <math.h>

#define B_ 2
#define S_ 2048
#define D_ 2048
#define H_ 16
#define HD_ 128
#define M_ (B_*S_)                 // 4096
#define BSD ((size_t)B_*S_*D_)     // 8388608 elements per output tensor

typedef short bf16x8 __attribute__((ext_vector_type(8)));   // 8 bf16 = 4 VGPRs
typedef float floatx4 __attribute__((ext_vector_type(4)));
typedef __hip_bfloat16 bf16;

union cv8 { bf16 h[8]; uint4 u; bf16x8 v; };

__device__ inline cv8 cvt8(const float4 a, const float4 b) {
    cv8 c;
    c.h[0] = __float2bfloat16(a.x); c.h[1] = __float2bfloat16(a.y);
    c.h[2] = __float2bfloat16(a.z); c.h[3] = __float2bfloat16(a.w);
    c.h[4] = __float2bfloat16(b.x); c.h[5] = __float2bfloat16(b.y);
    c.h[6] = __float2bfloat16(b.z); c.h[7] = __float2bfloat16(b.w);
    return c;
}

// async global->LDS, 16B per lane; lds dst = wave-uniform base + lane*16
__device__ __forceinline__ void gld16(const void* g, void* l) {
    __builtin_amdgcn_global_load_lds(
        (const __attribute__((address_space(1))) unsigned int*)g,
        (__attribute__((address_space(3))) unsigned int*)l,
        16, 0, 0);
}

// ---------------- W transpose+convert (plain, for fallback) -----------------
__global__ __launch_bounds__(256) void transpose_w(
    const float* __restrict__ W, bf16* __restrict__ Wt, int N, int K)
{
    __shared__ float T[32][33];
    const int k0 = blockIdx.x * 32, n0 = blockIdx.y * 32;
    const int r = threadIdx.x >> 3, c4 = (threadIdx.x & 7) * 4;
    float4 v = *(const float4*)&W[(size_t)(k0 + r) * N + n0 + c4];
    T[r][c4+0] = v.x; T[r][c4+1] = v.y; T[r][c4+2] = v.z; T[r][c4+3] = v.w;
    __syncthreads();
    union { bf16 h[4]; uint2 u; } o;
    #pragma unroll
    for (int i = 0; i < 4; ++i) o.h[i] = __float2bfloat16(T[c4 + i][r]);
    *(uint2*)&Wt[(size_t)(n0 + r) * K + k0 + c4] = o.u;
}

// ---------------- W transpose+convert, PRE-SWIZZLED rows --------------------
// Wt row n (4096B): within each 64B chunk, byte ^= ((n&3)<<4).
__global__ __launch_bounds__(256) void transpose_w_s(
    const float* __restrict__ W, bf16* __restrict__ Wt, int N, int K)
{
    __shared__ float T[32][33];
    const int k0 = blockIdx.x * 32, n0 = blockIdx.y * 32;
    const int r = threadIdx.x >> 3, c4 = (threadIdx.x & 7) * 4;
    float4 v = *(const float4*)&W[(size_t)(k0 + r) * N + n0 + c4];
    T[r][c4+0] = v.x; T[r][c4+1] = v.y; T[r][c4+2] = v.z; T[r][c4+3] = v.w;
    __syncthreads();
    union { bf16 h[4]; uint2 u; } o;
    #pragma unroll
    for (int i = 0; i < 4; ++i) o.h[i] = __float2bfloat16(T[c4 + i][r]);
    const int n = n0 + r;
    size_t bo = (size_t)n * (size_t)K * 2 + ((unsigned)((k0 + c4) * 2) ^ ((n & 3) << 4));
    *(uint2*)((char*)Wt + bo) = o.u;
}

// ---------------- pack x fp32 -> bf16, PRE-SWIZZLED (rows of 2048) ----------
__global__ __launch_bounds__(256) void pack_bf16(
    const float* __restrict__ src, bf16* __restrict__ dst)
{
    const size_t i = ((size_t)blockIdx.x * 256 + threadIdx.x) * 8;
    cv8 c = cvt8(*(const float4*)(src + i), *(const float4*)(src + i + 4));
    size_t bo = i * 2;                       // 16B aligned; row = bo>>12 (4096B rows)
    bo ^= (size_t)(((bo >> 12) & 3) << 4);
    *(uint4*)((char*)dst + bo) = c.u;
}

// ---- fused RoPE(K) + pack K -> [b,h,s,hd] bf16 PRE-SWIZZLED; K fp32 in-place
__global__ __launch_bounds__(256) void rope_pack_k(
    float* __restrict__ k, bf16* __restrict__ kbb,
    const float* __restrict__ cf, const float* __restrict__ sf,
    const int* __restrict__ pos)
{
    const int idx = blockIdx.x * 256 + threadIdx.x;   // B*S*H*8
    const int dg = idx & 7;                 // 8-wide group in low half
    const int h  = (idx >> 3) & (H_-1);
    const int bs = idx >> 7;
    const int s  = bs & (S_-1);
    const int b  = bs >> 11;
    const int p  = pos[bs];
    const size_t base = (size_t)bs * D_ + h*HD_ + dg*8;
    float lo[8], hi[8], c1[8], s1[8], c2[8], s2[8];
    *(float4*)&lo[0] = *(const float4*)&k[base];
    *(float4*)&lo[4] = *(const float4*)&k[base + 4];
    *(float4*)&hi[0] = *(const float4*)&k[base + 64];
    *(float4*)&hi[4] = *(const float4*)&k[base + 68];
    const float* cp = cf + (size_t)p*HD_ + dg*8;
    const float* sp = sf + (size_t)p*HD_ + dg*8;
    *(float4*)&c1[0] = *(const float4*)cp;        *(float4*)&c1[4] = *(const float4*)(cp + 4);
    *(float4*)&s1[0] = *(const float4*)sp;        *(float4*)&s1[4] = *(const float4*)(sp + 4);
    *(float4*)&c2[0] = *(const float4*)(cp + 64); *(float4*)&c2[4] = *(const float4*)(cp + 68);
    *(float4*)&s2[0] = *(const float4*)(sp + 64); *(float4*)&s2[4] = *(const float4*)(sp + 68);
    float nl[8], nh[8];
    #pragma unroll
    for (int j = 0; j < 8; ++j) {
        nl[j] = lo[j]*c1[j] - hi[j]*s1[j];
        nh[j] = hi[j]*c2[j] + lo[j]*s2[j];
    }
    *(float4*)&k[base]      = *(float4*)&nl[0];
    *(float4*)&k[base + 4]  = *(float4*)&nl[4];
    *(float4*)&k[base + 64] = *(float4*)&nh[0];
    *(float4*)&k[base + 68] = *(float4*)&nh[4];
    cv8 clo, chi;
    #pragma unroll
    for (int j = 0; j < 8; ++j) {
        clo.h[j] = __float2bfloat16(nl[j]);
        chi.h[j] = __float2bfloat16(nh[j]);
    }
    const size_t rowb = ((size_t)(b*H_ + h)*S_ + s) * (size_t)(HD_*2);
    *(uint4*)((char*)kbb + rowb + ((dg*16)       ^ ((s & 7) << 4))) = clo.u;
    *(uint4*)((char*)kbb + rowb + (((dg+8)*16)   ^ ((s & 7) << 4))) = chi.u;
}

// --- pack V^T: [b,s,h,hd] fp32 -> [b,h,hd,s] bf16, PRE-SWIZZLED 128B blocks -
// row hd: within each 128B block of the row, byte ^= ((hd&7)<<4)
__global__ __launch_bounds__(256) void pack_vt(
    const float* __restrict__ src, bf16* __restrict__ dst)
{
    __shared__ float T[32][33];
    const int s0 = blockIdx.x * 32;
    const int d0 = blockIdx.y * 32;
    const int bh = blockIdx.z;
    const int b = bh >> 4, h = bh & (H_-1);
    const int r = threadIdx.x >> 3, c4 = (threadIdx.x & 7) * 4;
    float4 v = *(const float4*)&src[((size_t)(b*S_ + s0 + r)*H_ + h)*HD_ + d0 + c4];
    T[r][c4+0] = v.x; T[r][c4+1] = v.y; T[r][c4+2] = v.z; T[r][c4+3] = v.w;
    __syncthreads();
    union { bf16 h4[4]; uint2 u; } o;
    #pragma unroll
    for (int i = 0; i < 4; ++i) o.h4[i] = __float2bfloat16(T[c4 + i][r]);
    const int hd = d0 + r;
    size_t rowb = ((size_t)bh*HD_ + hd) * (size_t)(S_*2);
    size_t colb = (size_t)(s0 + c4) * 2;
    colb = (colb & ~(size_t)127) | (((unsigned)colb & 127u) ^ (unsigned)((hd & 7) << 4));
    *(uint2*)((char*)dst + rowb + colb) = o.u;
}

// ---------------- GEMM (m97 pattern): C fp32 = A bf16 x Wt bf16 -------------
__global__ __launch_bounds__(256, 3) void gemm_bb2(
    const bf16* __restrict__ A, const bf16* __restrict__ Wt,
    float* __restrict__ C, int M, int N, int K)
{
    __shared__ __align__(16) bf16 As[128][32];   // linear, 64B rows (swizzled data)
    __shared__ __align__(16) bf16 Bs[128][32];
    const int nwg = (int)(gridDim.x * gridDim.y);
    int id = (int)(blockIdx.y * gridDim.x + blockIdx.x);
    if ((nwg & 7) == 0) id = (id & 7) * (nwg >> 3) + (id >> 3);   // XCD swizzle
    const int m0 = (id % (int)gridDim.x) * 128;
    const int n0 = (id / (int)gridDim.x) * 128;
    const int tid = threadIdx.x, lane = tid & 63, w = tid >> 6;
    const int quad = lane >> 4, l16 = lane & 15;
    const int wrow = (w >> 1) * 64, wcol = (w & 1) * 64;
    const size_t K2 = (size_t)K * 2;

    floatx4 acc[4][4] = {};

    const char* Ab = (const char*)A;
    const char* Bb = (const char*)Wt;
    char* AsB = (char*)&As[0][0];
    char* BsB = (char*)&Bs[0][0];
    const int srow = lane >> 2;              // 16 rows per 1KB issue
    const int scol = (lane & 3) * 16;

    for (int kt = 0; kt < K; kt += 32) {
        #pragma unroll
        for (int j = 0; j < 2; ++j) {
            const int row = w*32 + j*16 + srow;
            gld16(Ab + (size_t)(m0 + row)*K2 + (size_t)(kt*2) + scol,
                  AsB + w*2048 + j*1024);
            gld16(Bb + (size_t)(n0 + row)*K2 + (size_t)(kt*2) + scol,
                  BsB + w*2048 + j*1024);
        }
        __syncthreads();

        bf16x8 af[4], bfr[4];
        #pragma unroll
        for (int t = 0; t < 4; ++t) {
            const int ra = wrow + t*16 + l16;
            af[t]  = *(const bf16x8*)(AsB + ra*64 + ((quad*16) ^ ((ra & 3) << 4)));
            const int rb = wcol + t*16 + l16;
            bfr[t] = *(const bf16x8*)(BsB + rb*64 + ((quad*16) ^ ((rb & 3) << 4)));
        }
        #pragma unroll
        for (int mt = 0; mt < 4; ++mt)
            #pragma unroll
            for (int nt = 0; nt < 4; ++nt)
                acc[mt][nt] = __builtin_amdgcn_mfma_f32_16x16x32_bf16(
                    af[mt], bfr[nt], acc[mt][nt], 0, 0, 0);
        __syncthreads();
    }

    #pragma unroll
    for (int mt = 0; mt < 4; ++mt)
        #pragma unroll
        for (int nt = 0; nt < 4; ++nt)
            #pragma unroll
            for (int r = 0; r < 4; ++r)
                C[(size_t)(m0 + wrow + mt*16 + quad*4 + r) * N
                  + n0 + wcol + nt*16 + l16] = acc[mt][nt][r];
}

// ---------------- GEMM v2 (fallback): A fp32, Wt bf16 (unswizzled) ----------
__global__ __launch_bounds__(256) void gemm_xw(
    const float* __restrict__ A, const bf16* __restrict__ Wt,
    float* __restrict__ C, int M, int N, int K)
{
    __shared__ __align__(16) bf16 As[128][40];
    __shared__ __align__(16) bf16 Bs[128][40];
    const int m0 = blockIdx.x * 128, n0 = blockIdx.y * 128;
    const int tid = threadIdx.x, lane = tid & 63, w = tid >> 6;
    const int quad = lane >> 4, l16 = lane & 15;
    const int wrow = (w >> 1) * 64, wcol = (w & 1) * 64;
    floatx4 acc[4][4] = {};
    const int arow = tid >> 2;
    const int acol = (tid & 3) * 8;
    for (int kt = 0; kt < K; kt += 32) {
        #pragma unroll
        for (int p = 0; p < 2; ++p) {
            const int r = p*64 + arow;
            const float* ap = &A[(size_t)(m0 + r) * K + kt + acol];
            cv8 ca = cvt8(*(const float4*)ap, *(const float4*)(ap + 4));
            *(uint4*)&As[r][acol] = ca.u;
            const bf16* bp = &Wt[(size_t)(n0 + r) * K + kt + acol];
            *(uint4*)&Bs[r][acol] = *(const uint4*)bp;
        }
        __syncthreads();
        bf16x8 af[4], bfr[4];
        #pragma unroll
        for (int t = 0; t < 4; ++t) {
            af[t]  = *(const bf16x8*)&As[wrow + t*16 + l16][quad*8];
            bfr[t] = *(const bf16x8*)&Bs[wcol + t*16 + l16][quad*8];
        }
        #pragma unroll
        for (int mt = 0; mt < 4; ++mt)
            #pragma unroll
            for (int nt = 0; nt < 4; ++nt)
                acc[mt][nt] = __builtin_amdgcn_mfma_f32_16x16x32_bf16(
                    af[mt], bfr[nt], acc[mt][nt], 0, 0, 0);
        __syncthreads();
    }
    #pragma unroll
    for (int mt = 0; mt < 4; ++mt)
        #pragma unroll
        for (int nt = 0; nt < 4; ++nt)
            #pragma unroll
            for (int r = 0; r < 4; ++r)
                C[(size_t)(m0 + wrow + mt*16 + quad*4 + r) * N
                  + n0 + wcol + nt*16 + l16] = acc[mt][nt][r];
}

// ---------------- GEMM v1 (fallback, small ws): inline W transpose ----------
__global__ __launch_bounds__(256) void gemm_f32(
    const float* __restrict__ A, const float* __restrict__ W,
    float* __restrict__ C, int M, int N, int K)
{
    __shared__ __align__(16) bf16 As[64][40];
    __shared__ __align__(16) bf16 Bs[64][40];
    const int m0 = blockIdx.x * 64, n0 = blockIdx.y * 64;
    const int tid = threadIdx.x, lane = tid & 63, w = tid >> 6;
    const int quad = lane >> 4, l16 = lane & 15;
    const int wrow = (w >> 1) * 32, wcol = (w & 1) * 32;
    floatx4 acc[2][2] = {};
    const int ar = tid >> 2, ac = (tid & 3) * 8;
    const int br = tid >> 3, bc = (tid & 7) * 8;
    for (int kt = 0; kt < K; kt += 32) {
        {
            const float* ap = &A[(size_t)(m0 + ar) * K + kt + ac];
            cv8 c = cvt8(*(const float4*)ap, *(const float4*)(ap + 4));
            *(uint4*)&As[ar][ac] = c.u;
        }
        {
            const float* wp = &W[(size_t)(kt + br) * N + n0 + bc];
            cv8 c = cvt8(*(const float4*)wp, *(const float4*)(wp + 4));
            #pragma unroll
            for (int i = 0; i < 8; ++i) Bs[bc + i][br] = c.h[i];
        }
        __syncthreads();
        bf16x8 af[2], bfr[2];
        #pragma unroll
        for (int t = 0; t < 2; ++t) {
            af[t]  = *(const bf16x8*)&As[wrow + t*16 + l16][quad*8];
            bfr[t] = *(const bf16x8*)&Bs[wcol + t*16 + l16][quad*8];
        }
        #pragma unroll
        for (int mt = 0; mt < 2; ++mt)
            #pragma unroll
            for (int nt = 0; nt < 2; ++nt)
                acc[mt][nt] = __builtin_amdgcn_mfma_f32_16x16x32_bf16(
                    af[mt], bfr[nt], acc[mt][nt], 0, 0, 0);
        __syncthreads();
    }
    #pragma unroll
    for (int mt = 0; mt < 2; ++mt)
        #pragma unroll
        for (int nt = 0; nt < 2; ++nt)
            #pragma unroll
            for (int r = 0; r < 4; ++r)
                C[(size_t)(m0 + wrow + mt*16 + quad*4 + r) * N
                  + n0 + wcol + nt*16 + l16] = acc[mt][nt][r];
}

// ---------------- RoPE q+k (fallback paths) ---------------------------------
__global__ __launch_bounds__(256) void rope_kernel(
    float* __restrict__ q, float* __restrict__ k,
    const float* __restrict__ cf, const float* __restrict__ sf,
    const int* __restrict__ pos)
{
    const int PAIRS = B_*S_*H_*(HD_/2);
    int idx = blockIdx.x * 256 + threadIdx.x;
    float* t = q;
    if (idx >= PAIRS) { t = k; idx -= PAIRS; }
    const int d  = idx & 63;
    const int h  = (idx >> 6) & (H_-1);
    const int bs = idx >> 10;
    const int p  = pos[bs];
    const float c1 = cf[p*HD_ + d],      s1 = sf[p*HD_ + d];
    const float c2 = cf[p*HD_ + d + 64], s2 = sf[p*HD_ + d + 64];
    const size_t base = (size_t)bs * D_ + h*HD_ + d;
    const float t1 = t[base], t2 = t[base + 64];
    t[base]      = t1*c1 - t2*s1;
    t[base + 64] = t2*c2 + t1*s2;
}

// ---------------- Flash attention v5 ----------------------------------------
// One barrier per k-tile. K and V^T double-buffered in LDS via global_load_lds;
// Ps is per-wave (no cross-wave exchange -> no mid barrier). K fragments are
// hoisted to registers before the prefetch DMAs are issued so QK never waits;
// V fragments are hoisted after softmax. Base-2 online softmax (exp2f ->
// v_exp_f32, the native base-2 HW transcendental).
__global__ __launch_bounds__(256, 2) void flash_attn_v5(
    const float* __restrict__ qg, const bf16* __restrict__ kb,
    const bf16* __restrict__ vb, bf16* __restrict__ ob,
    const float* __restrict__ cf, const float* __restrict__ sf,
    const int* __restrict__ pos)
{
    __shared__ __align__(16) bf16 Ks[2][64][128];   // 32KB, swizzled rows
    __shared__ __align__(16) bf16 Vt[2][128][64];   // 32KB, swizzled rows
    __shared__ __align__(16) bf16 Ps[4][16][72];    // 9KB, per-wave slices

    const int qi = (int)gridDim.x - 1 - (int)blockIdx.x;  // heavy tiles first
    const int q0 = qi * 64;
    const int bh = blockIdx.y;
    const int b = bh >> 4, h = bh & (H_-1);
    const int tid = threadIdx.x, lane = tid & 63, w = tid >> 6;
    const int quad = lane >> 4, l16 = lane & 15;

    const char* kbase = (const char*)(kb + (size_t)bh * S_ * HD_);
    const char* vbase = (const char*)(vb + (size_t)bh * HD_ * S_);
    char* ksd = (char*)&Ks[0][0][0];
    char* vtd = (char*)&Vt[0][0][0];

    const int klofs = w*4096;                 // wave chunk in 16KB K tile
    const int vrow0 = w*32 + (lane >> 3);     // V^T staging row
    const int vcb   = (lane & 7) * 16;

    // prologue: stage K(0), V(0) into buffer 0 (DMA overlaps Q-RoPE below)
    #pragma unroll
    for (int j = 0; j < 4; ++j)
        gld16(kbase + klofs + j*1024 + lane*16, ksd + klofs + j*1024);
    #pragma unroll
    for (int j = 0; j < 4; ++j)
        gld16(vbase + (size_t)(vrow0 + j*8)*(S_*2) + vcb, vtd + w*4096 + j*1024);

    // Q load + fused RoPE + bf16 convert
    const int qrow = q0 + w*16 + l16;
    const float* qptr = qg + ((size_t)(b*S_ + qrow))*D_ + h*HD_;
    float rq[4][8];
    #pragma unroll
    for (int c = 0; c < 4; ++c) {
        const float* qp = qptr + c*32 + quad*8;
        *(float4*)&rq[c][0] = *(const float4*)qp;
        *(float4*)&rq[c][4] = *(const float4*)(qp + 4);
    }
    const int p = pos[b*S_ + qrow];
    bf16x8 qf[4];
    #pragma unroll
    for (int c = 0; c < 4; ++c) {
        const float* cp = cf + (size_t)p*HD_ + c*32 + quad*8;
        const float* sp = sf + (size_t)p*HD_ + c*32 + quad*8;
        float cc[8], ss[8];
        *(float4*)&cc[0] = *(const float4*)cp; *(float4*)&cc[4] = *(const float4*)(cp+4);
        *(float4*)&ss[0] = *(const float4*)sp; *(float4*)&ss[4] = *(const float4*)(sp+4);
        cv8 cv;
        #pragma unroll
        for (int j = 0; j < 8; ++j) {
            const float o = (c < 2) ? rq[c][j]*cc[j] - rq[c^2][j]*ss[j]
                                    : rq[c][j]*cc[j] + rq[c^2][j]*ss[j];
            cv.h[j] = __float2bfloat16(o);
        }
        qf[c] = cv.v;
    }

    floatx4 acc_o[8] = {};
    float m_run[4], l_run[4];
    #pragma unroll
    for (int r = 0; r < 4; ++r) { m_run[r] = -30000.0f; l_run[r] = 0.f; }

    // scale folded with log2(e): softmax runs in base 2
    const float SCL2 = 0.08838834764831845f * 1.4426950408889634f;

    __syncthreads();   // K(0), V(0) resident & visible

    for (int kt = 0; kt <= qi; ++kt) {
        const int cur = kt & 1;
        const char* ksb = ksd + cur*16384;
        const char* vtb = vtd + cur*16384;

        // 1) hoist K fragments (resident buffer -> zero-wait ds_reads)
        bf16x8 kf[4][4];
        #pragma unroll
        for (int c = 0; c < 4; ++c)
            #pragma unroll
            for (int kc = 0; kc < 4; ++kc)
                kf[c][kc] = *(const bf16x8*)(ksb + (c*16 + l16)*256
                              + ((kc*64 + quad*16) ^ ((l16 & 7) << 4)));

        // 2) issue next-tile DMAs into the other buffers
        if (kt < qi) {
            const char* ksrc = kbase + (size_t)(kt+1)*16384;
            char* kdst = ksd + (cur^1)*16384;
            #pragma unroll
            for (int j = 0; j < 4; ++j)
                gld16(ksrc + klofs + j*1024 + lane*16, kdst + klofs + j*1024);
            const char* vsrc = vbase + (size_t)(kt+1)*128;
            char* vdst = vtd + (cur^1)*16384;
            #pragma unroll
            for (int j = 0; j < 4; ++j)
                gld16(vsrc + (size_t)(vrow0 + j*8)*(S_*2) + vcb,
                      vdst + w*4096 + j*1024);
        }

        // 3) S = Q K^T from registers
        floatx4 sc[4] = {};
        __builtin_amdgcn_s_setprio(1);
        #pragma unroll
        for (int c = 0; c < 4; ++c)
            #pragma unroll
            for (int kc = 0; kc < 4; ++kc)
                sc[c] = __builtin_amdgcn_mfma_f32_16x16x32_bf16(qf[kc], kf[c][kc], sc[c], 0, 0, 0);
        __builtin_amdgcn_s_setprio(0);

        // 4) base-2 online softmax
        const int k0 = kt * 64;
        float pv[4][4], mt_[4];
        #pragma unroll
        for (int r = 0; r < 4; ++r) mt_[r] = -30000.0f;
        #pragma unroll
        for (int c = 0; c < 4; ++c) {
            const int kcol = k0 + c*16 + l16;
            #pragma unroll
            for (int r = 0; r < 4; ++r) {
                const int qr = q0 + w*16 + quad*4 + r;
                float s = sc[c][r] * SCL2;
                if (kcol > qr) s = -30000.0f;
                pv[c][r] = s;
                mt_[r] = fmaxf(mt_[r], s);
            }
        }
        #pragma unroll
        for (int off = 1; off < 16; off <<= 1)
            #pragma unroll
            for (int r = 0; r < 4; ++r)
                mt_[r] = fmaxf(mt_[r], __shfl_xor(mt_[r], off, 64));
        float alpha[4];
        #pragma unroll
        for (int r = 0; r < 4; ++r) {
            float mn = fmaxf(m_run[r], mt_[r]);
            alpha[r] = exp2f(m_run[r] - mn);
            m_run[r] = mn;
        }
        #pragma unroll
        for (int c = 0; c < 4; ++c)
            #pragma unroll
            for (int r = 0; r < 4; ++r)
                pv[c][r] = exp2f(pv[c][r] - m_run[r]);
        #pragma unroll
        for (int r = 0; r < 4; ++r) {
            float s = pv[0][r] + pv[1][r] + pv[2][r] + pv[3][r];
            #pragma unroll
            for (int off = 1; off < 16; off <<= 1)
                s += __shfl_xor(s, off, 64);
            l_run[r] = l_run[r] * alpha[r] + s;
        }
        // Ps is a per-wave slice: write->read ordered by lgkmcnt, no barrier
        #pragma unroll
        for (int c = 0; c < 4; ++c)
            #pragma unroll
            for (int r = 0; r < 4; ++r)
                Ps[w][quad*4 + r][c*16 + l16] = __float2bfloat16(pv[c][r]);

        // 5) rescale O, hoist V fragments + P fragments, PV MFMAs
        #pragma unroll
        for (int n = 0; n < 8; ++n)
            #pragma unroll
            for (int r = 0; r < 4; ++r)
                acc_o[n][r] *= alpha[r];
        bf16x8 pf[2];
        #pragma unroll
        for (int kc2 = 0; kc2 < 2; ++kc2)
            pf[kc2] = *(const bf16x8*)&Ps[w][l16][kc2*32 + quad*8];
        bf16x8 vf[8][2];
        #pragma unroll
        for (int n = 0; n < 8; ++n)
            #pragma unroll
            for (int kc2 = 0; kc2 < 2; ++kc2)
                vf[n][kc2] = *(const bf16x8*)(vtb + (n*16 + l16)*128
                               + ((kc2*64 + quad*16) ^ ((l16 & 7) << 4)));
        __builtin_amdgcn_s_setprio(1);
        #pragma unroll
        for (int n = 0; n < 8; ++n)
            #pragma unroll
            for (int kc2 = 0; kc2 < 2; ++kc2)
                acc_o[n] = __builtin_amdgcn_mfma_f32_16x16x32_bf16(pf[kc2], vf[n][kc2], acc_o[n], 0, 0, 0);
        __builtin_amdgcn_s_setprio(0);

        // 6) single barrier: drains next-tile DMAs (covered by this iter's
        //    compute) and fences buffer swap across waves
        __syncthreads();
    }

    float inv[4];
    #pragma unroll
    for (int r = 0; r < 4; ++r) inv[r] = 1.0f / l_run[r];
    #pragma unroll
    for (int n = 0; n < 8; ++n)
        #pragma unroll
        for (int r = 0; r < 4; ++r) {
            const int qr = q0 + w*16 + quad*4 + r;
            // pre-swizzled for gemm_bb2 A-read: byte ^= ((m&3)<<4), m&3 == r
            size_t bo = ((((size_t)(b*S_ + qr))*D_ + h*HD_ + n*16 + l16) * 2)
                        ^ (size_t)(r << 4);
            *(bf16*)((char*)ob + bo) = __float2bfloat16(acc_o[n][r] * inv[r]);
        }
}

// ---------------- Flash attention v2 (fallback, fp32 K/V) -------------------
__global__ __launch_bounds__(256) void flash_attn(
    const float* qg, const float* __restrict__ kg,
    const float* __restrict__ vg, float* og)
{
    __shared__ __align__(16) bf16 Ks[64][136];
    __shared__ __align__(16) bf16 Vt[128][72];
    __shared__ __align__(16) bf16 Ps[4][16][72];

    const int qi = (int)gridDim.x - 1 - (int)blockIdx.x;
    const int q0 = qi * 64;
    const int bh = blockIdx.y;
    const int b = bh >> 4, h = bh & (H_-1);
    const int tid = threadIdx.x, lane = tid & 63, w = tid >> 6;
    const int quad = lane >> 4, l16 = lane & 15;

    const int qrow = q0 + w*16 + l16;
    const float* qptr = qg + ((size_t)(b*S_ + qrow)*H_ + h)*HD_;
    bf16x8 qf[4];
    #pragma unroll
    for (int c = 0; c < 4; ++c) {
        const float* qp = qptr + c*32 + quad*8;
        cv8 cv = cvt8(*(const float4*)qp, *(const float4*)(qp + 4));
        qf[c] = cv.v;
    }

    floatx4 acc_o[8] = {};
    float m_run[4], l_run[4];
    #pragma unroll
    for (int r = 0; r < 4; ++r) { m_run[r] = -30000.0f; l_run[r] = 0.f; }

    const int ksr = tid >> 2, kscg = (tid & 3) * 32;
    const int vk2 = (tid & 31) * 2, vf8 = (tid >> 5) * 8;

    for (int kt = 0; kt <= qi; ++kt) {
        const int k0 = kt * 64;
        {
            const float* kp = kg + ((size_t)(b*S_ + k0 + ksr)*H_ + h)*HD_ + kscg;
            #pragma unroll
            for (int j = 0; j < 4; ++j) {
                cv8 c = cvt8(*(const float4*)(kp + j*8), *(const float4*)(kp + j*8 + 4));
                *(uint4*)&Ks[ksr][kscg + j*8] = c.u;
            }
        }
        {
            #pragma unroll
            for (int pq = 0; pq < 2; ++pq) {
                const int f = vf8 + pq*64;
                const float* v0p = vg + ((size_t)(b*S_ + k0 + vk2)*H_ + h)*HD_ + f;
                const float* v1p = v0p + D_;
                cv8 c0 = cvt8(*(const float4*)v0p, *(const float4*)(v0p + 4));
                cv8 c1 = cvt8(*(const float4*)v1p, *(const float4*)(v1p + 4));
                #pragma unroll
                for (int i = 0; i < 8; ++i) {
                    union { bf16 h2[2]; unsigned u; } pk;
                    pk.h2[0] = c0.h[i]; pk.h2[1] = c1.h[i];
                    *(unsigned*)&Vt[f + i][vk2] = pk.u;
                }
            }
        }
        __syncthreads();

        floatx4 sc[4] = {};
        #pragma unroll
        for (int c = 0; c < 4; ++c)
            #pragma unroll
            for (int kc = 0; kc < 4; ++kc) {
                bf16x8 kf = *(const bf16x8*)&Ks[c*16 + l16][kc*32 + quad*8];
                sc[c] = __builtin_amdgcn_mfma_f32_16x16x32_bf16(qf[kc], kf, sc[c], 0, 0, 0);
            }

        float pv[4][4], mt_[4];
        #pragma unroll
        for (int r = 0; r < 4; ++r) mt_[r] = -30000.0f;
        #pragma unroll
        for (int c = 0; c < 4; ++c) {
            const int kcol = k0 + c*16 + l16;
            #pragma unroll
            for (int r = 0; r < 4; ++r) {
                const int qr = q0 + w*16 + quad*4 + r;
                float s = sc[c][r] * 0.08838834764831845f;
                if (kcol > qr) s = -30000.0f;
                pv[c][r] = s;
                mt_[r] = fmaxf(mt_[r], s);
            }
        }
        #pragma unroll
        for (int off = 1; off < 16; off <<= 1)
            #pragma unroll
            for (int r = 0; r < 4; ++r)
                mt_[r] = fmaxf(mt_[r], __shfl_xor(mt_[r], off, 64));
        float alpha[4];
        #pragma unroll
        for (int r = 0; r < 4; ++r) {
            float mn = fmaxf(m_run[r], mt_[r]);
            alpha[r] = __expf(m_run[r] - mn);
            m_run[r] = mn;
        }
        #pragma unroll
        for (int c = 0; c < 4; ++c)
            #pragma unroll
            for (int r = 0; r < 4; ++r)
                pv[c][r] = __expf(pv[c][r] - m_run[r]);
        #pragma unroll
        for (int r = 0; r < 4; ++r) {
            float s = pv[0][r] + pv[1][r] + pv[2][r] + pv[3][r];
            #pragma unroll
            for (int off = 1; off < 16; off <<= 1)
                s += __shfl_xor(s, off, 64);
            l_run[r] = l_run[r] * alpha[r] + s;
        }
        #pragma unroll
        for (int c = 0; c < 4; ++c)
            #pragma unroll
            for (int r = 0; r < 4; ++r)
                Ps[w][quad*4 + r][c*16 + l16] = __float2bfloat16(pv[c][r]);
        __syncthreads();

        #pragma unroll
        for (int n = 0; n < 8; ++n)
            #pragma unroll
            for (int r = 0; r < 4; ++r)
                acc_o[n][r] *= alpha[r];
        bf16x8 pf[2];
        #pragma unroll
        for (int kc2 = 0; kc2 < 2; ++kc2)
            pf[kc2] = *(const bf16x8*)&Ps[w][l16][kc2*32 + quad*8];
        #pragma unroll
        for (int n = 0; n < 8; ++n)
            #pragma unroll
            for (int kc2 = 0; kc2 < 2; ++kc2) {
                bf16x8 vf = *(const bf16x8*)&Vt[n*16 + l16][kc2*32 + quad*8];
                acc_o[n] = __builtin_amdgcn_mfma_f32_16x16x32_bf16(pf[kc2], vf, acc_o[n], 0, 0, 0);
            }
        __syncthreads();
    }

    #pragma unroll
    for (int n = 0; n < 8; ++n)
        #pragma unroll
        for (int r = 0; r < 4; ++r) {
            const int qr = q0 + w*16 + quad*4 + r;
            og[((size_t)(b*S_ + qr))*D_ + h*HD_ + n*16 + l16] = acc_o[n][r] / l_run[r];
        }
}

// ---------------------------------------------------------------------------
extern "C" void kernel_launch(void* const* d_in, const int* in_sizes, int n_in,
                              void* d_out, int out_size, void* d_ws, size_t ws_size,
                              hipStream_t stream) {
    const float* x  = (const float*)d_in[0];
    const float* cf = (const float*)d_in[1];
    const float* sf = (const float*)d_in[2];
    const float* Wq = (const float*)d_in[3];
    const float* Wk = (const float*)d_in[4];
    const float* Wv = (const float*)d_in[5];
    const float* Wo = (const float*)d_in[6];
    const int*  pos = (const int*)d_in[7];

    float* out  = (float*)d_out;        // final; interim: Q (pre-RoPE)
    float* kout = out + BSD;            // fp32 K cache output (post-RoPE)
    float* vout = out + 2*BSD;          // fp32 V cache output

    const size_t WT_BYTES = (size_t)D_ * D_ * sizeof(bf16);   // 8 MB
    const size_t TB_BYTES = BSD * sizeof(bf16);               // 16 MB bf16 tensor
    const size_t NEED_V5  = WT_BYTES + 4 * TB_BYTES;          // ~72 MB
    const bool big = ws_size >= WT_BYTES + (size_t)128 * D_ * sizeof(float);

    if (ws_size >= NEED_V5) {
        bf16* wt  = (bf16*)d_ws;
        bf16* xb  = wt + (size_t)D_ * D_;     // x bf16 (pre-swizzled)
        bf16* kbb = xb + BSD;                 // K bf16 [b,h,s,hd] (pre-swizzled)
        bf16* vbb = kbb + BSD;                // V^T bf16 [b,h,hd,s] (pre-swizzled)
        bf16* obb = vbb + BSD;                // attn-out bf16 (pre-swizzled)

        dim3 tg(D_/32, D_/32), gg(M_/128, D_/128);
        pack_bf16<<<(int)(BSD/8/256), 256, 0, stream>>>(x, xb);
        transpose_w_s<<<tg, 256, 0, stream>>>(Wq, wt, D_, D_);
        gemm_bb2<<<gg, 256, 0, stream>>>(xb, wt, out,  M_, D_, D_);
        transpose_w_s<<<tg, 256, 0, stream>>>(Wk, wt, D_, D_);
        gemm_bb2<<<gg, 256, 0, stream>>>(xb, wt, kout, M_, D_, D_);
        transpose_w_s<<<tg, 256, 0, stream>>>(Wv, wt, D_, D_);
        gemm_bb2<<<gg, 256, 0, stream>>>(xb, wt, vout, M_, D_, D_);
        rope_pack_k<<<(B_*S_*H_*8)/256, 256, 0, stream>>>(kout, kbb, cf, sf, pos);
        pack_vt<<<dim3(S_/32, HD_/32, B_*H_), 256, 0, stream>>>(vout, vbb);
        flash_attn_v5<<<dim3(S_/64, B_*H_), 256, 0, stream>>>(out, kbb, vbb, obb,
                                                              cf, sf, pos);
        transpose_w_s<<<tg, 256, 0, stream>>>(Wo, wt, D_, D_);
        gemm_bb2<<<gg, 256, 0, stream>>>(obb, wt, out, M_, D_, D_);
    } else if (big) {
        bf16*  wt  = (bf16*)d_ws;
        float* cws = (float*)((char*)d_ws + WT_BYTES);
        const size_t crem = ws_size - WT_BYTES;
        dim3 tg(D_/32, D_/32), gg(M_/128, D_/128);
        transpose_w<<<tg, 256, 0, stream>>>(Wq, wt, D_, D_);
        gemm_xw<<<gg, 256, 0, stream>>>(x, wt, out,  M_, D_, D_);
        transpose_w<<<tg, 256, 0, stream>>>(Wk, wt, D_, D_);
        gemm_xw<<<gg, 256, 0, stream>>>(x, wt, kout, M_, D_, D_);
        transpose_w<<<tg, 256, 0, stream>>>(Wv, wt, D_, D_);
        gemm_xw<<<gg, 256, 0, stream>>>(x, wt, vout, M_, D_, D_);
        rope_kernel<<<(2*B_*S_*H_*(HD_/2))/256, 256, 0, stream>>>(out, kout, cf, sf, pos);
        flash_attn<<<dim3(S_/64, B_*H_), 256, 0, stream>>>(out, kout, vout, out);
        transpose_w<<<tg, 256, 0, stream>>>(Wo, wt, D_, D_);
        int R = 128;
        while (R < M_ && (size_t)(2*R) * D_ * sizeof(float) <= crem) R *= 2;
        for (int m0 = 0; m0 < M_; m0 += R) {
            gemm_xw<<<dim3(R/128, D_/128), 256, 0, stream>>>(out + (size_t)m0*D_, wt, cws, R, D_, D_);
            hipMemcpyAsync(out + (size_t)m0*D_, cws, (size_t)R*D_*sizeof(float),
                           hipMemcpyDeviceToDevice, stream);
        }
    } else {
        float* wsb = (float*)d_ws;
        dim3 gg(M_/64, D_/64);
        gemm_f32<<<gg, 256, 0, stream>>>(x, Wq, out,  M_, D_, D_);
        gemm_f32<<<gg, 256, 0, stream>>>(x, Wk, kout, M_, D_, D_);
        gemm_f32<<<gg, 256, 0, stream>>>(x, Wv, vout, M_, D_, D_);
        rope_kernel<<<(2*B_*S_*H_*(HD_/2))/256, 256, 0, stream>>>(out, kout, cf, sf, pos);
        flash_attn<<<dim3(S_/64, B_*H_), 256, 0, stream>>>(out, kout, vout, out);
        int R = 64;
        while (R < M_ && (size_t)(2*R) * D_ * sizeof(float) <= ws_size) R *= 2;
        if ((size_t)R * D_ * sizeof(float) > ws_size) R = 64;
        for (int m0 = 0; m0 < M_; m0 += R) {
            gemm_f32<<<dim3(R/64, D_/64), 256, 0, stream>>>(out + (size_t)m0*D_, Wo, wsb, R, D_, D_);
            hipMemcpyAsync(out + (size_t)m0*D_, wsb, (size_t)R*D_*sizeof(float),
                           hipMemcpyDeviceToDevice, stream);
        }
    }
}

// Round 6
// 557.107 us; speedup vs baseline: 1.0638x; 1.0638x over previous
//
#include <hip/hip_runtime.h>
#include <hip/hip_bf16.h>

#define B_ 2
#define S_ 2048
#define D_ 2048
#define H_ 16
#define HD_ 128
#define M_ (B_*S_)                 // 4096
#define BSD ((size_t)B_*S_*D_)     // 8388608 elements per output tensor

typedef short bf16x8 __attribute__((ext_vector_type(8)));   // 8 bf16 = 4 VGPRs
typedef float floatx4 __attribute__((ext_vector_type(4)));
typedef __hip_bfloat16 bf16;

union cv8 { bf16 h[8]; uint4 u; bf16x8 v; };

__device__ inline cv8 cvt8(const float4 a, const float4 b) {
    cv8 c;
    c.h[0] = __float2bfloat16(a.x); c.h[1] = __float2bfloat16(a.y);
    c.h[2] = __float2bfloat16(a.z); c.h[3] = __float2bfloat16(a.w);
    c.h[4] = __float2bfloat16(b.x); c.h[5] = __float2bfloat16(b.y);
    c.h[6] = __float2bfloat16(b.z); c.h[7] = __float2bfloat16(b.w);
    return c;
}

// async global->LDS, 16B per lane; lds dst = wave-uniform base + lane*16
__device__ __forceinline__ void gld16(const void* g, void* l) {
    __builtin_amdgcn_global_load_lds(
        (const __attribute__((address_space(1))) unsigned int*)g,
        (__attribute__((address_space(3))) unsigned int*)l,
        16, 0, 0);
}

// ---------------- W transpose+convert (plain, for fallback) -----------------
__global__ __launch_bounds__(256) void transpose_w(
    const float* __restrict__ W, bf16* __restrict__ Wt, int N, int K)
{
    __shared__ float T[32][33];
    const int k0 = blockIdx.x * 32, n0 = blockIdx.y * 32;
    const int r = threadIdx.x >> 3, c4 = (threadIdx.x & 7) * 4;
    float4 v = *(const float4*)&W[(size_t)(k0 + r) * N + n0 + c4];
    T[r][c4+0] = v.x; T[r][c4+1] = v.y; T[r][c4+2] = v.z; T[r][c4+3] = v.w;
    __syncthreads();
    union { bf16 h[4]; uint2 u; } o;
    #pragma unroll
    for (int i = 0; i < 4; ++i) o.h[i] = __float2bfloat16(T[c4 + i][r]);
    *(uint2*)&Wt[(size_t)(n0 + r) * K + k0 + c4] = o.u;
}

// ---------------- W transpose+convert, PRE-SWIZZLED rows --------------------
// Wt row n (4096B): within each 64B chunk, byte ^= ((n&3)<<4).
__global__ __launch_bounds__(256) void transpose_w_s(
    const float* __restrict__ W, bf16* __restrict__ Wt, int N, int K)
{
    __shared__ float T[32][33];
    const int k0 = blockIdx.x * 32, n0 = blockIdx.y * 32;
    const int r = threadIdx.x >> 3, c4 = (threadIdx.x & 7) * 4;
    float4 v = *(const float4*)&W[(size_t)(k0 + r) * N + n0 + c4];
    T[r][c4+0] = v.x; T[r][c4+1] = v.y; T[r][c4+2] = v.z; T[r][c4+3] = v.w;
    __syncthreads();
    union { bf16 h[4]; uint2 u; } o;
    #pragma unroll
    for (int i = 0; i < 4; ++i) o.h[i] = __float2bfloat16(T[c4 + i][r]);
    const int n = n0 + r;
    size_t bo = (size_t)n * (size_t)K * 2 + ((unsigned)((k0 + c4) * 2) ^ ((n & 3) << 4));
    *(uint2*)((char*)Wt + bo) = o.u;
}

// ---------------- pack x fp32 -> bf16, PRE-SWIZZLED (rows of 2048) ----------
__global__ __launch_bounds__(256) void pack_bf16(
    const float* __restrict__ src, bf16* __restrict__ dst)
{
    const size_t i = ((size_t)blockIdx.x * 256 + threadIdx.x) * 8;
    cv8 c = cvt8(*(const float4*)(src + i), *(const float4*)(src + i + 4));
    size_t bo = i * 2;                       // 16B aligned; row = bo>>12 (4096B rows)
    bo ^= (size_t)(((bo >> 12) & 3) << 4);
    *(uint4*)((char*)dst + bo) = c.u;
}

// ---- fused RoPE(K) + pack K -> [b,h,s,hd] bf16 PRE-SWIZZLED; K fp32 in-place
__global__ __launch_bounds__(256) void rope_pack_k(
    float* __restrict__ k, bf16* __restrict__ kbb,
    const float* __restrict__ cf, const float* __restrict__ sf,
    const int* __restrict__ pos)
{
    const int idx = blockIdx.x * 256 + threadIdx.x;   // B*S*H*8
    const int dg = idx & 7;                 // 8-wide group in low half
    const int h  = (idx >> 3) & (H_-1);
    const int bs = idx >> 7;
    const int s  = bs & (S_-1);
    const int b  = bs >> 11;
    const int p  = pos[bs];
    const size_t base = (size_t)bs * D_ + h*HD_ + dg*8;
    float lo[8], hi[8], c1[8], s1[8], c2[8], s2[8];
    *(float4*)&lo[0] = *(const float4*)&k[base];
    *(float4*)&lo[4] = *(const float4*)&k[base + 4];
    *(float4*)&hi[0] = *(const float4*)&k[base + 64];
    *(float4*)&hi[4] = *(const float4*)&k[base + 68];
    const float* cp = cf + (size_t)p*HD_ + dg*8;
    const float* sp = sf + (size_t)p*HD_ + dg*8;
    *(float4*)&c1[0] = *(const float4*)cp;        *(float4*)&c1[4] = *(const float4*)(cp + 4);
    *(float4*)&s1[0] = *(const float4*)sp;        *(float4*)&s1[4] = *(const float4*)(sp + 4);
    *(float4*)&c2[0] = *(const float4*)(cp + 64); *(float4*)&c2[4] = *(const float4*)(cp + 68);
    *(float4*)&s2[0] = *(const float4*)(sp + 64); *(float4*)&s2[4] = *(const float4*)(sp + 68);
    float nl[8], nh[8];
    #pragma unroll
    for (int j = 0; j < 8; ++j) {
        nl[j] = lo[j]*c1[j] - hi[j]*s1[j];
        nh[j] = hi[j]*c2[j] + lo[j]*s2[j];
    }
    *(float4*)&k[base]      = *(float4*)&nl[0];
    *(float4*)&k[base + 4]  = *(float4*)&nl[4];
    *(float4*)&k[base + 64] = *(float4*)&nh[0];
    *(float4*)&k[base + 68] = *(float4*)&nh[4];
    cv8 clo, chi;
    #pragma unroll
    for (int j = 0; j < 8; ++j) {
        clo.h[j] = __float2bfloat16(nl[j]);
        chi.h[j] = __float2bfloat16(nh[j]);
    }
    const size_t rowb = ((size_t)(b*H_ + h)*S_ + s) * (size_t)(HD_*2);
    *(uint4*)((char*)kbb + rowb + ((dg*16)       ^ ((s & 7) << 4))) = clo.u;
    *(uint4*)((char*)kbb + rowb + (((dg+8)*16)   ^ ((s & 7) << 4))) = chi.u;
}

// --- pack V^T: [b,s,h,hd] fp32 -> [b,h,hd,s] bf16, PRE-SWIZZLED 128B blocks -
// row hd: within each 128B block of the row, byte ^= ((hd&7)<<4)
__global__ __launch_bounds__(256) void pack_vt(
    const float* __restrict__ src, bf16* __restrict__ dst)
{
    __shared__ float T[32][33];
    const int s0 = blockIdx.x * 32;
    const int d0 = blockIdx.y * 32;
    const int bh = blockIdx.z;
    const int b = bh >> 4, h = bh & (H_-1);
    const int r = threadIdx.x >> 3, c4 = (threadIdx.x & 7) * 4;
    float4 v = *(const float4*)&src[((size_t)(b*S_ + s0 + r)*H_ + h)*HD_ + d0 + c4];
    T[r][c4+0] = v.x; T[r][c4+1] = v.y; T[r][c4+2] = v.z; T[r][c4+3] = v.w;
    __syncthreads();
    union { bf16 h4[4]; uint2 u; } o;
    #pragma unroll
    for (int i = 0; i < 4; ++i) o.h4[i] = __float2bfloat16(T[c4 + i][r]);
    const int hd = d0 + r;
    size_t rowb = ((size_t)bh*HD_ + hd) * (size_t)(S_*2);
    size_t colb = (size_t)(s0 + c4) * 2;
    colb = (colb & ~(size_t)127) | (((unsigned)colb & 127u) ^ (unsigned)((hd & 7) << 4));
    *(uint2*)((char*)dst + rowb + colb) = o.u;
}

// ---------------- GEMM (m97 pattern): C fp32 = A bf16 x Wt bf16 -------------
__global__ __launch_bounds__(256, 3) void gemm_bb2(
    const bf16* __restrict__ A, const bf16* __restrict__ Wt,
    float* __restrict__ C, int M, int N, int K)
{
    __shared__ __align__(16) bf16 As[128][32];   // linear, 64B rows (swizzled data)
    __shared__ __align__(16) bf16 Bs[128][32];
    const int nwg = (int)(gridDim.x * gridDim.y);
    int id = (int)(blockIdx.y * gridDim.x + blockIdx.x);
    if ((nwg & 7) == 0) id = (id & 7) * (nwg >> 3) + (id >> 3);   // XCD swizzle
    const int m0 = (id % (int)gridDim.x) * 128;
    const int n0 = (id / (int)gridDim.x) * 128;
    const int tid = threadIdx.x, lane = tid & 63, w = tid >> 6;
    const int quad = lane >> 4, l16 = lane & 15;
    const int wrow = (w >> 1) * 64, wcol = (w & 1) * 64;
    const size_t K2 = (size_t)K * 2;

    floatx4 acc[4][4] = {};

    const char* Ab = (const char*)A;
    const char* Bb = (const char*)Wt;
    char* AsB = (char*)&As[0][0];
    char* BsB = (char*)&Bs[0][0];
    const int srow = lane >> 2;              // 16 rows per 1KB issue
    const int scol = (lane & 3) * 16;

    for (int kt = 0; kt < K; kt += 32) {
        #pragma unroll
        for (int j = 0; j < 2; ++j) {
            const int row = w*32 + j*16 + srow;
            gld16(Ab + (size_t)(m0 + row)*K2 + (size_t)(kt*2) + scol,
                  AsB + w*2048 + j*1024);
            gld16(Bb + (size_t)(n0 + row)*K2 + (size_t)(kt*2) + scol,
                  BsB + w*2048 + j*1024);
        }
        __syncthreads();

        bf16x8 af[4], bfr[4];
        #pragma unroll
        for (int t = 0; t < 4; ++t) {
            const int ra = wrow + t*16 + l16;
            af[t]  = *(const bf16x8*)(AsB + ra*64 + ((quad*16) ^ ((ra & 3) << 4)));
            const int rb = wcol + t*16 + l16;
            bfr[t] = *(const bf16x8*)(BsB + rb*64 + ((quad*16) ^ ((rb & 3) << 4)));
        }
        #pragma unroll
        for (int mt = 0; mt < 4; ++mt)
            #pragma unroll
            for (int nt = 0; nt < 4; ++nt)
                acc[mt][nt] = __builtin_amdgcn_mfma_f32_16x16x32_bf16(
                    af[mt], bfr[nt], acc[mt][nt], 0, 0, 0);
        __syncthreads();
    }

    #pragma unroll
    for (int mt = 0; mt < 4; ++mt)
        #pragma unroll
        for (int nt = 0; nt < 4; ++nt)
            #pragma unroll
            for (int r = 0; r < 4; ++r)
                C[(size_t)(m0 + wrow + mt*16 + quad*4 + r) * N
                  + n0 + wcol + nt*16 + l16] = acc[mt][nt][r];
}

// ---------------- GEMM v2 (fallback): A fp32, Wt bf16 (unswizzled) ----------
__global__ __launch_bounds__(256) void gemm_xw(
    const float* __restrict__ A, const bf16* __restrict__ Wt,
    float* __restrict__ C, int M, int N, int K)
{
    __shared__ __align__(16) bf16 As[128][40];
    __shared__ __align__(16) bf16 Bs[128][40];
    const int m0 = blockIdx.x * 128, n0 = blockIdx.y * 128;
    const int tid = threadIdx.x, lane = tid & 63, w = tid >> 6;
    const int quad = lane >> 4, l16 = lane & 15;
    const int wrow = (w >> 1) * 64, wcol = (w & 1) * 64;
    floatx4 acc[4][4] = {};
    const int arow = tid >> 2;
    const int acol = (tid & 3) * 8;
    for (int kt = 0; kt < K; kt += 32) {
        #pragma unroll
        for (int p = 0; p < 2; ++p) {
            const int r = p*64 + arow;
            const float* ap = &A[(size_t)(m0 + r) * K + kt + acol];
            cv8 ca = cvt8(*(const float4*)ap, *(const float4*)(ap + 4));
            *(uint4*)&As[r][acol] = ca.u;
            const bf16* bp = &Wt[(size_t)(n0 + r) * K + kt + acol];
            *(uint4*)&Bs[r][acol] = *(const uint4*)bp;
        }
        __syncthreads();
        bf16x8 af[4], bfr[4];
        #pragma unroll
        for (int t = 0; t < 4; ++t) {
            af[t]  = *(const bf16x8*)&As[wrow + t*16 + l16][quad*8];
            bfr[t] = *(const bf16x8*)&Bs[wcol + t*16 + l16][quad*8];
        }
        #pragma unroll
        for (int mt = 0; mt < 4; ++mt)
            #pragma unroll
            for (int nt = 0; nt < 4; ++nt)
                acc[mt][nt] = __builtin_amdgcn_mfma_f32_16x16x32_bf16(
                    af[mt], bfr[nt], acc[mt][nt], 0, 0, 0);
        __syncthreads();
    }
    #pragma unroll
    for (int mt = 0; mt < 4; ++mt)
        #pragma unroll
        for (int nt = 0; nt < 4; ++nt)
            #pragma unroll
            for (int r = 0; r < 4; ++r)
                C[(size_t)(m0 + wrow + mt*16 + quad*4 + r) * N
                  + n0 + wcol + nt*16 + l16] = acc[mt][nt][r];
}

// ---------------- GEMM v1 (fallback, small ws): inline W transpose ----------
__global__ __launch_bounds__(256) void gemm_f32(
    const float* __restrict__ A, const float* __restrict__ W,
    float* __restrict__ C, int M, int N, int K)
{
    __shared__ __align__(16) bf16 As[64][40];
    __shared__ __align__(16) bf16 Bs[64][40];
    const int m0 = blockIdx.x * 64, n0 = blockIdx.y * 64;
    const int tid = threadIdx.x, lane = tid & 63, w = tid >> 6;
    const int quad = lane >> 4, l16 = lane & 15;
    const int wrow = (w >> 1) * 32, wcol = (w & 1) * 32;
    floatx4 acc[2][2] = {};
    const int ar = tid >> 2, ac = (tid & 3) * 8;
    const int br = tid >> 3, bc = (tid & 7) * 8;
    for (int kt = 0; kt < K; kt += 32) {
        {
            const float* ap = &A[(size_t)(m0 + ar) * K + kt + ac];
            cv8 c = cvt8(*(const float4*)ap, *(const float4*)(ap + 4));
            *(uint4*)&As[ar][ac] = c.u;
        }
        {
            const float* wp = &W[(size_t)(kt + br) * N + n0 + bc];
            cv8 c = cvt8(*(const float4*)wp, *(const float4*)(wp + 4));
            #pragma unroll
            for (int i = 0; i < 8; ++i) Bs[bc + i][br] = c.h[i];
        }
        __syncthreads();
        bf16x8 af[2], bfr[2];
        #pragma unroll
        for (int t = 0; t < 2; ++t) {
            af[t]  = *(const bf16x8*)&As[wrow + t*16 + l16][quad*8];
            bfr[t] = *(const bf16x8*)&Bs[wcol + t*16 + l16][quad*8];
        }
        #pragma unroll
        for (int mt = 0; mt < 2; ++mt)
            #pragma unroll
            for (int nt = 0; nt < 2; ++nt)
                acc[mt][nt] = __builtin_amdgcn_mfma_f32_16x16x32_bf16(
                    af[mt], bfr[nt], acc[mt][nt], 0, 0, 0);
        __syncthreads();
    }
    #pragma unroll
    for (int mt = 0; mt < 2; ++mt)
        #pragma unroll
        for (int nt = 0; nt < 2; ++nt)
            #pragma unroll
            for (int r = 0; r < 4; ++r)
                C[(size_t)(m0 + wrow + mt*16 + quad*4 + r) * N
                  + n0 + wcol + nt*16 + l16] = acc[mt][nt][r];
}

// ---------------- RoPE q+k (fallback paths) ---------------------------------
__global__ __launch_bounds__(256) void rope_kernel(
    float* __restrict__ q, float* __restrict__ k,
    const float* __restrict__ cf, const float* __restrict__ sf,
    const int* __restrict__ pos)
{
    const int PAIRS = B_*S_*H_*(HD_/2);
    int idx = blockIdx.x * 256 + threadIdx.x;
    float* t = q;
    if (idx >= PAIRS) { t = k; idx -= PAIRS; }
    const int d  = idx & 63;
    const int h  = (idx >> 6) & (H_-1);
    const int bs = idx >> 10;
    const int p  = pos[bs];
    const float c1 = cf[p*HD_ + d],      s1 = sf[p*HD_ + d];
    const float c2 = cf[p*HD_ + d + 64], s2 = sf[p*HD_ + d + 64];
    const size_t base = (size_t)bs * D_ + h*HD_ + d;
    const float t1 = t[base], t2 = t[base + 64];
    t[base]      = t1*c1 - t2*s1;
    t[base + 64] = t2*c2 + t1*s2;
}

// ---------------- Flash attention v6: swapped-QK in-register softmax --------
// mfma(K,Q) -> S^T fragment: each lane owns q-row = l16, kcols = c*16+quad*4+r.
// Softmax is per-lane (scalar m/l state, 2 shfl_xor reduce). P is repacked to
// the PV A-fragment with 16 shfls; no Ps LDS buffer -> 48KB LDS, 3 blocks/CU.
// K double-buffered, V single-buffered (v4-proven barrier schedule).
__global__ __launch_bounds__(256, 3) void flash_attn_v6(
    const float* __restrict__ qg, const bf16* __restrict__ kb,
    const bf16* __restrict__ vb, bf16* __restrict__ ob,
    const float* __restrict__ cf, const float* __restrict__ sf,
    const int* __restrict__ pos)
{
    __shared__ __align__(16) bf16 Ks[2][64][128];   // 32KB dbuf, swizzled rows
    __shared__ __align__(16) bf16 Vt[128][64];      // 16KB single, swizzled

    const int qi = (int)gridDim.x - 1 - (int)blockIdx.x;  // heavy tiles first
    const int q0 = qi * 64;
    const int bh = blockIdx.y;
    const int b = bh >> 4, h = bh & (H_-1);
    const int tid = threadIdx.x, lane = tid & 63, w = tid >> 6;
    const int quad = lane >> 4, l16 = lane & 15;

    const char* kbase = (const char*)(kb + (size_t)bh * S_ * HD_);
    const char* vbase = (const char*)(vb + (size_t)bh * HD_ * S_);
    char* ksd = (char*)&Ks[0][0][0];
    char* vtd = (char*)&Vt[0][0];

    const int klofs = w*4096;                 // wave chunk in 16KB K tile
    const int vrow0 = w*32 + (lane >> 3);     // V^T staging row
    const int vcb   = (lane & 7) * 16;

    // prologue: stage K(0) into buffer 0 (DMA overlaps Q-RoPE below)
    #pragma unroll
    for (int j = 0; j < 4; ++j)
        gld16(kbase + klofs + j*1024 + lane*16, ksd + klofs + j*1024);

    // Q load + fused RoPE + bf16 convert (fragment: [row=l16][k=quad*8+j])
    const int qrow = q0 + w*16 + l16;
    const float* qptr = qg + ((size_t)(b*S_ + qrow))*D_ + h*HD_;
    float rq[4][8];
    #pragma unroll
    for (int c = 0; c < 4; ++c) {
        const float* qp = qptr + c*32 + quad*8;
        *(float4*)&rq[c][0] = *(const float4*)qp;
        *(float4*)&rq[c][4] = *(const float4*)(qp + 4);
    }
    const int p = pos[b*S_ + qrow];
    bf16x8 qf[4];
    #pragma unroll
    for (int c = 0; c < 4; ++c) {
        const float* cp = cf + (size_t)p*HD_ + c*32 + quad*8;
        const float* sp = sf + (size_t)p*HD_ + c*32 + quad*8;
        float cc[8], ss[8];
        *(float4*)&cc[0] = *(const float4*)cp; *(float4*)&cc[4] = *(const float4*)(cp+4);
        *(float4*)&ss[0] = *(const float4*)sp; *(float4*)&ss[4] = *(const float4*)(sp+4);
        cv8 cv;
        #pragma unroll
        for (int j = 0; j < 8; ++j) {
            const float o = (c < 2) ? rq[c][j]*cc[j] - rq[c^2][j]*ss[j]
                                    : rq[c][j]*cc[j] + rq[c^2][j]*ss[j];
            cv.h[j] = __float2bfloat16(o);
        }
        qf[c] = cv.v;
    }

    floatx4 acc_o[8] = {};
    float m_run = -30000.0f, l_run = 0.0f;    // per-lane: q-row = l16
    const int qr_sm = q0 + w*16 + l16;
    const float SCL = 0.08838834764831845f;

    __syncthreads();   // K(0) resident & visible

    for (int kt = 0; kt <= qi; ++kt) {
        const int cur = kt & 1;
        const char* ksb = ksd + cur*16384;

        if (kt < qi) {   // prefetch next K tile into other buffer
            const char* ksrc = kbase + (size_t)(kt+1)*16384;
            char* kdst = ksd + (cur^1)*16384;
            #pragma unroll
            for (int j = 0; j < 4; ++j)
                gld16(ksrc + klofs + j*1024 + lane*16, kdst + klofs + j*1024);
        }
        {   // stage V(kt) (read only after mid-barrier)
            const char* vsrc = vbase + (size_t)kt*128;
            #pragma unroll
            for (int j = 0; j < 4; ++j)
                gld16(vsrc + (size_t)(vrow0 + j*8)*(S_*2) + vcb,
                      vtd + w*4096 + j*1024);
        }

        // S^T = K Q^T : lane holds S[qrow=l16][kcol=c*16+quad*4+r]
        floatx4 sc[4] = {};
        __builtin_amdgcn_s_setprio(1);
        #pragma unroll
        for (int c = 0; c < 4; ++c)
            #pragma unroll
            for (int kc = 0; kc < 4; ++kc) {
                bf16x8 kf = *(const bf16x8*)(ksb + (c*16 + l16)*256
                              + ((kc*64 + quad*16) ^ ((l16 & 7) << 4)));
                sc[c] = __builtin_amdgcn_mfma_f32_16x16x32_bf16(kf, qf[kc], sc[c], 0, 0, 0);
            }
        __builtin_amdgcn_s_setprio(0);

        // per-lane online softmax (row = l16); reduce across the 4 quads only
        const int k0 = kt * 64;
        float pv[4][4], mt = -30000.0f;
        #pragma unroll
        for (int c = 0; c < 4; ++c)
            #pragma unroll
            for (int r = 0; r < 4; ++r) {
                const int kcol = k0 + c*16 + quad*4 + r;
                float s = sc[c][r] * SCL;
                if (kcol > qr_sm) s = -30000.0f;
                pv[c][r] = s;
                mt = fmaxf(mt, s);
            }
        mt = fmaxf(mt, __shfl_xor(mt, 16, 64));
        mt = fmaxf(mt, __shfl_xor(mt, 32, 64));
        const float mn = fmaxf(m_run, mt);
        const float alpha = __expf(m_run - mn);
        m_run = mn;
        float sum = 0.0f;
        #pragma unroll
        for (int c = 0; c < 4; ++c)
            #pragma unroll
            for (int r = 0; r < 4; ++r) {
                pv[c][r] = __expf(pv[c][r] - mn);
                sum += pv[c][r];
            }
        sum += __shfl_xor(sum, 16, 64);
        sum += __shfl_xor(sum, 32, 64);
        l_run = l_run * alpha + sum;

        // rescale O: alpha lives at lane l16=qrow; acc rows are quad*4+r
        float at[4];
        #pragma unroll
        for (int r = 0; r < 4; ++r) at[r] = __shfl(alpha, quad*4 + r, 64);
        #pragma unroll
        for (int n = 0; n < 8; ++n)
            #pragma unroll
            for (int r = 0; r < 4; ++r)
                acc_o[n][r] *= at[r];

        // pack P to bf16 pairs: pk[c][p2] = (pv[c][2p2], pv[c][2p2+1])
        unsigned pk[4][2];
        #pragma unroll
        for (int c = 0; c < 4; ++c) {
            union { bf16 h2[2]; unsigned u; } a0, a1;
            a0.h2[0] = __float2bfloat16(pv[c][0]); a0.h2[1] = __float2bfloat16(pv[c][1]);
            a1.h2[0] = __float2bfloat16(pv[c][2]); a1.h2[1] = __float2bfloat16(pv[c][3]);
            pk[c][0] = a0.u; pk[c][1] = a1.u;
        }
        // build PV A-fragments: word u of pf[kc2] holds k = kc2*32+quad*8+2u+{0,1}
        //   = source (c_src = kc2*2 + (quad>>1), quad_src = (quad&1)*2 + (u>>1),
        //      pair = u&1) at lane quad_src*16 + l16
        bf16x8 pf[2];
        #pragma unroll
        for (int kc2 = 0; kc2 < 2; ++kc2) {
            union { unsigned u[4]; bf16x8 v; } wv;
            #pragma unroll
            for (int u_ = 0; u_ < 4; ++u_) {
                const int sl = ((quad & 1)*2 + (u_ >> 1))*16 + l16;
                const unsigned w0 = __shfl(pk[kc2*2 + 0][u_ & 1], sl, 64);
                const unsigned w1 = __shfl(pk[kc2*2 + 1][u_ & 1], sl, 64);
                wv.u[u_] = (quad >> 1) ? w1 : w0;
            }
            pf[kc2] = wv.v;
        }

        __syncthreads();   // drains V(kt) + K(kt+1) DMAs; fences buffers

        __builtin_amdgcn_s_setprio(1);
        #pragma unroll
        for (int n = 0; n < 8; ++n)
            #pragma unroll
            for (int kc2 = 0; kc2 < 2; ++kc2) {
                bf16x8 vf = *(const bf16x8*)(vtd + (n*16 + l16)*128
                               + ((kc2*64 + quad*16) ^ ((l16 & 7) << 4)));
                acc_o[n] = __builtin_amdgcn_mfma_f32_16x16x32_bf16(pf[kc2], vf, acc_o[n], 0, 0, 0);
            }
        __builtin_amdgcn_s_setprio(0);

        __syncthreads();   // PV reads done before next iter's staging writes
    }

    const float linv = 1.0f / l_run;
    float lt[4];
    #pragma unroll
    for (int r = 0; r < 4; ++r) lt[r] = __shfl(linv, quad*4 + r, 64);
    #pragma unroll
    for (int n = 0; n < 8; ++n)
        #pragma unroll
        for (int r = 0; r < 4; ++r) {
            const int qr = q0 + w*16 + quad*4 + r;
            // pre-swizzled for gemm_bb2 A-read: byte ^= ((m&3)<<4), m&3 == r
            size_t bo = ((((size_t)(b*S_ + qr))*D_ + h*HD_ + n*16 + l16) * 2)
                        ^ (size_t)(r << 4);
            *(bf16*)((char*)ob + bo) = __float2bfloat16(acc_o[n][r] * lt[r]);
        }
}

// ---------------- Flash attention v2 (fallback, fp32 K/V) -------------------
__global__ __launch_bounds__(256) void flash_attn(
    const float* qg, const float* __restrict__ kg,
    const float* __restrict__ vg, float* og)
{
    __shared__ __align__(16) bf16 Ks[64][136];
    __shared__ __align__(16) bf16 Vt[128][72];
    __shared__ __align__(16) bf16 Ps[4][16][72];

    const int qi = (int)gridDim.x - 1 - (int)blockIdx.x;
    const int q0 = qi * 64;
    const int bh = blockIdx.y;
    const int b = bh >> 4, h = bh & (H_-1);
    const int tid = threadIdx.x, lane = tid & 63, w = tid >> 6;
    const int quad = lane >> 4, l16 = lane & 15;

    const int qrow = q0 + w*16 + l16;
    const float* qptr = qg + ((size_t)(b*S_ + qrow)*H_ + h)*HD_;
    bf16x8 qf[4];
    #pragma unroll
    for (int c = 0; c < 4; ++c) {
        const float* qp = qptr + c*32 + quad*8;
        cv8 cv = cvt8(*(const float4*)qp, *(const float4*)(qp + 4));
        qf[c] = cv.v;
    }

    floatx4 acc_o[8] = {};
    float m_run[4], l_run[4];
    #pragma unroll
    for (int r = 0; r < 4; ++r) { m_run[r] = -30000.0f; l_run[r] = 0.f; }

    const int ksr = tid >> 2, kscg = (tid & 3) * 32;
    const int vk2 = (tid & 31) * 2, vf8 = (tid >> 5) * 8;

    for (int kt = 0; kt <= qi; ++kt) {
        const int k0 = kt * 64;
        {
            const float* kp = kg + ((size_t)(b*S_ + k0 + ksr)*H_ + h)*HD_ + kscg;
            #pragma unroll
            for (int j = 0; j < 4; ++j) {
                cv8 c = cvt8(*(const float4*)(kp + j*8), *(const float4*)(kp + j*8 + 4));
                *(uint4*)&Ks[ksr][kscg + j*8] = c.u;
            }
        }
        {
            #pragma unroll
            for (int pq = 0; pq < 2; ++pq) {
                const int f = vf8 + pq*64;
                const float* v0p = vg + ((size_t)(b*S_ + k0 + vk2)*H_ + h)*HD_ + f;
                const float* v1p = v0p + D_;
                cv8 c0 = cvt8(*(const float4*)v0p, *(const float4*)(v0p + 4));
                cv8 c1 = cvt8(*(const float4*)v1p, *(const float4*)(v1p + 4));
                #pragma unroll
                for (int i = 0; i < 8; ++i) {
                    union { bf16 h2[2]; unsigned u; } pk;
                    pk.h2[0] = c0.h[i]; pk.h2[1] = c1.h[i];
                    *(unsigned*)&Vt[f + i][vk2] = pk.u;
                }
            }
        }
        __syncthreads();

        floatx4 sc[4] = {};
        #pragma unroll
        for (int c = 0; c < 4; ++c)
            #pragma unroll
            for (int kc = 0; kc < 4; ++kc) {
                bf16x8 kf = *(const bf16x8*)&Ks[c*16 + l16][kc*32 + quad*8];
                sc[c] = __builtin_amdgcn_mfma_f32_16x16x32_bf16(qf[kc], kf, sc[c], 0, 0, 0);
            }

        float pv[4][4], mt_[4];
        #pragma unroll
        for (int r = 0; r < 4; ++r) mt_[r] = -30000.0f;
        #pragma unroll
        for (int c = 0; c < 4; ++c) {
            const int kcol = k0 + c*16 + l16;
            #pragma unroll
            for (int r = 0; r < 4; ++r) {
                const int qr = q0 + w*16 + quad*4 + r;
                float s = sc[c][r] * 0.08838834764831845f;
                if (kcol > qr) s = -30000.0f;
                pv[c][r] = s;
                mt_[r] = fmaxf(mt_[r], s);
            }
        }
        #pragma unroll
        for (int off = 1; off < 16; off <<= 1)
            #pragma unroll
            for (int r = 0; r < 4; ++r)
                mt_[r] = fmaxf(mt_[r], __shfl_xor(mt_[r], off, 64));
        float alpha[4];
        #pragma unroll
        for (int r = 0; r < 4; ++r) {
            float mn = fmaxf(m_run[r], mt_[r]);
            alpha[r] = __expf(m_run[r] - mn);
            m_run[r] = mn;
        }
        #pragma unroll
        for (int c = 0; c < 4; ++c)
            #pragma unroll
            for (int r = 0; r < 4; ++r)
                pv[c][r] = __expf(pv[c][r] - m_run[r]);
        #pragma unroll
        for (int r = 0; r < 4; ++r) {
            float s = pv[0][r] + pv[1][r] + pv[2][r] + pv[3][r];
            #pragma unroll
            for (int off = 1; off < 16; off <<= 1)
                s += __shfl_xor(s, off, 64);
            l_run[r] = l_run[r] * alpha[r] + s;
        }
        #pragma unroll
        for (int c = 0; c < 4; ++c)
            #pragma unroll
            for (int r = 0; r < 4; ++r)
                Ps[w][quad*4 + r][c*16 + l16] = __float2bfloat16(pv[c][r]);
        __syncthreads();

        #pragma unroll
        for (int n = 0; n < 8; ++n)
            #pragma unroll
            for (int r = 0; r < 4; ++r)
                acc_o[n][r] *= alpha[r];
        bf16x8 pf[2];
        #pragma unroll
        for (int kc2 = 0; kc2 < 2; ++kc2)
            pf[kc2] = *(const bf16x8*)&Ps[w][l16][kc2*32 + quad*8];
        #pragma unroll
        for (int n = 0; n < 8; ++n)
            #pragma unroll
            for (int kc2 = 0; kc2 < 2; ++kc2) {
                bf16x8 vf = *(const bf16x8*)&Vt[n*16 + l16][kc2*32 + quad*8];
                acc_o[n] = __builtin_amdgcn_mfma_f32_16x16x32_bf16(pf[kc2], vf, acc_o[n], 0, 0, 0);
            }
        __syncthreads();
    }

    #pragma unroll
    for (int n = 0; n < 8; ++n)
        #pragma unroll
        for (int r = 0; r < 4; ++r) {
            const int qr = q0 + w*16 + quad*4 + r;
            og[((size_t)(b*S_ + qr))*D_ + h*HD_ + n*16 + l16] = acc_o[n][r] / l_run[r];
        }
}

// ---------------------------------------------------------------------------
extern "C" void kernel_launch(void* const* d_in, const int* in_sizes, int n_in,
                              void* d_out, int out_size, void* d_ws, size_t ws_size,
                              hipStream_t stream) {
    const float* x  = (const float*)d_in[0];
    const float* cf = (const float*)d_in[1];
    const float* sf = (const float*)d_in[2];
    const float* Wq = (const float*)d_in[3];
    const float* Wk = (const float*)d_in[4];
    const float* Wv = (const float*)d_in[5];
    const float* Wo = (const float*)d_in[6];
    const int*  pos = (const int*)d_in[7];

    float* out  = (float*)d_out;        // final; interim: Q (pre-RoPE)
    float* kout = out + BSD;            // fp32 K cache output (post-RoPE)
    float* vout = out + 2*BSD;          // fp32 V cache output

    const size_t WT_BYTES = (size_t)D_ * D_ * sizeof(bf16);   // 8 MB
    const size_t TB_BYTES = BSD * sizeof(bf16);               // 16 MB bf16 tensor
    const size_t NEED_V6  = WT_BYTES + 4 * TB_BYTES;          // ~72 MB
    const bool big = ws_size >= WT_BYTES + (size_t)128 * D_ * sizeof(float);

    if (ws_size >= NEED_V6) {
        bf16* wt  = (bf16*)d_ws;
        bf16* xb  = wt + (size_t)D_ * D_;     // x bf16 (pre-swizzled)
        bf16* kbb = xb + BSD;                 // K bf16 [b,h,s,hd] (pre-swizzled)
        bf16* vbb = kbb + BSD;                // V^T bf16 [b,h,hd,s] (pre-swizzled)
        bf16* obb = vbb + BSD;                // attn-out bf16 (pre-swizzled)

        dim3 tg(D_/32, D_/32), gg(M_/128, D_/128);
        pack_bf16<<<(int)(BSD/8/256), 256, 0, stream>>>(x, xb);
        transpose_w_s<<<tg, 256, 0, stream>>>(Wq, wt, D_, D_);
        gemm_bb2<<<gg, 256, 0, stream>>>(xb, wt, out,  M_, D_, D_);
        transpose_w_s<<<tg, 256, 0, stream>>>(Wk, wt, D_, D_);
        gemm_bb2<<<gg, 256, 0, stream>>>(xb, wt, kout, M_, D_, D_);
        transpose_w_s<<<tg, 256, 0, stream>>>(Wv, wt, D_, D_);
        gemm_bb2<<<gg, 256, 0, stream>>>(xb, wt, vout, M_, D_, D_);
        rope_pack_k<<<(B_*S_*H_*8)/256, 256, 0, stream>>>(kout, kbb, cf, sf, pos);
        pack_vt<<<dim3(S_/32, HD_/32, B_*H_), 256, 0, stream>>>(vout, vbb);
        flash_attn_v6<<<dim3(S_/64, B_*H_), 256, 0, stream>>>(out, kbb, vbb, obb,
                                                              cf, sf, pos);
        transpose_w_s<<<tg, 256, 0, stream>>>(Wo, wt, D_, D_);
        gemm_bb2<<<gg, 256, 0, stream>>>(obb, wt, out, M_, D_, D_);
    } else if (big) {
        bf16*  wt  = (bf16*)d_ws;
        float* cws = (float*)((char*)d_ws + WT_BYTES);
        const size_t crem = ws_size - WT_BYTES;
        dim3 tg(D_/32, D_/32), gg(M_/128, D_/128);
        transpose_w<<<tg, 256, 0, stream>>>(Wq, wt, D_, D_);
        gemm_xw<<<gg, 256, 0, stream>>>(x, wt, out,  M_, D_, D_);
        transpose_w<<<tg, 256, 0, stream>>>(Wk, wt, D_, D_);
        gemm_xw<<<gg, 256, 0, stream>>>(x, wt, kout, M_, D_, D_);
        transpose_w<<<tg, 256, 0, stream>>>(Wv, wt, D_, D_);
        gemm_xw<<<gg, 256, 0, stream>>>(x, wt, vout, M_, D_, D_);
        rope_kernel<<<(2*B_*S_*H_*(HD_/2))/256, 256, 0, stream>>>(out, kout, cf, sf, pos);
        flash_attn<<<dim3(S_/64, B_*H_), 256, 0, stream>>>(out, kout, vout, out);
        transpose_w<<<tg, 256, 0, stream>>>(Wo, wt, D_, D_);
        int R = 128;
        while (R < M_ && (size_t)(2*R) * D_ * sizeof(float) <= crem) R *= 2;
        for (int m0 = 0; m0 < M_; m0 += R) {
            gemm_xw<<<dim3(R/128, D_/128), 256, 0, stream>>>(out + (size_t)m0*D_, wt, cws, R, D_, D_);
            hipMemcpyAsync(out + (size_t)m0*D_, cws, (size_t)R*D_*sizeof(float),
                           hipMemcpyDeviceToDevice, stream);
        }
    } else {
        float* wsb = (float*)d_ws;
        dim3 gg(M_/64, D_/64);
        gemm_f32<<<gg, 256, 0, stream>>>(x, Wq, out,  M_, D_, D_);
        gemm_f32<<<gg, 256, 0, stream>>>(x, Wk, kout, M_, D_, D_);
        gemm_f32<<<gg, 256, 0, stream>>>(x, Wv, vout, M_, D_, D_);
        rope_kernel<<<(2*B_*S_*H_*(HD_/2))/256, 256, 0, stream>>>(out, kout, cf, sf, pos);
        flash_attn<<<dim3(S_/64, B_*H_), 256, 0, stream>>>(out, kout, vout, out);
        int R = 64;
        while (R < M_ && (size_t)(2*R) * D_ * sizeof(float) <= ws_size) R *= 2;
        if ((size_t)R * D_ * sizeof(float) > ws_size) R = 64;
        for (int m0 = 0; m0 < M_; m0 += R) {
            gemm_f32<<<dim3(R/64, D_/64), 256, 0, stream>>>(out + (size_t)m0*D_, Wo, wsb, R, D_, D_);
            hipMemcpyAsync(out + (size_t)m0*D_, wsb, (size_t)R*D_*sizeof(float),
                           hipMemcpyDeviceToDevice, stream);
        }
    }
}

// Round 7
// 532.347 us; speedup vs baseline: 1.1133x; 1.0465x over previous
//
#include <hip/hip_runtime.h>
#include <hip/hip_bf16.h>

#define B_ 2
#define S_ 2048
#define D_ 2048
#define H_ 16
#define HD_ 128
#define M_ (B_*S_)                 // 4096
#define BSD ((size_t)B_*S_*D_)     // 8388608 elements per output tensor

typedef short bf16x8 __attribute__((ext_vector_type(8)));   // 8 bf16 = 4 VGPRs
typedef float floatx4 __attribute__((ext_vector_type(4)));
typedef __hip_bfloat16 bf16;

union cv8 { bf16 h[8]; uint4 u; bf16x8 v; };

__device__ inline cv8 cvt8(const float4 a, const float4 b) {
    cv8 c;
    c.h[0] = __float2bfloat16(a.x); c.h[1] = __float2bfloat16(a.y);
    c.h[2] = __float2bfloat16(a.z); c.h[3] = __float2bfloat16(a.w);
    c.h[4] = __float2bfloat16(b.x); c.h[5] = __float2bfloat16(b.y);
    c.h[6] = __float2bfloat16(b.z); c.h[7] = __float2bfloat16(b.w);
    return c;
}

// async global->LDS, 16B per lane; lds dst = wave-uniform base + lane*16
__device__ __forceinline__ void gld16(const void* g, void* l) {
    __builtin_amdgcn_global_load_lds(
        (const __attribute__((address_space(1))) unsigned int*)g,
        (__attribute__((address_space(3))) unsigned int*)l,
        16, 0, 0);
}

// ---------------- W transpose+convert (plain, for fallback) -----------------
__global__ __launch_bounds__(256) void transpose_w(
    const float* __restrict__ W, bf16* __restrict__ Wt, int N, int K)
{
    __shared__ float T[32][33];
    const int k0 = blockIdx.x * 32, n0 = blockIdx.y * 32;
    const int r = threadIdx.x >> 3, c4 = (threadIdx.x & 7) * 4;
    float4 v = *(const float4*)&W[(size_t)(k0 + r) * N + n0 + c4];
    T[r][c4+0] = v.x; T[r][c4+1] = v.y; T[r][c4+2] = v.z; T[r][c4+3] = v.w;
    __syncthreads();
    union { bf16 h[4]; uint2 u; } o;
    #pragma unroll
    for (int i = 0; i < 4; ++i) o.h[i] = __float2bfloat16(T[c4 + i][r]);
    *(uint2*)&Wt[(size_t)(n0 + r) * K + k0 + c4] = o.u;
}

// ---------------- W transpose+convert, PRE-SWIZZLED rows --------------------
// Wt row n (4096B): within each 64B chunk, byte ^= ((n&3)<<4).
__global__ __launch_bounds__(256) void transpose_w_s(
    const float* __restrict__ W, bf16* __restrict__ Wt, int N, int K)
{
    __shared__ float T[32][33];
    const int k0 = blockIdx.x * 32, n0 = blockIdx.y * 32;
    const int r = threadIdx.x >> 3, c4 = (threadIdx.x & 7) * 4;
    float4 v = *(const float4*)&W[(size_t)(k0 + r) * N + n0 + c4];
    T[r][c4+0] = v.x; T[r][c4+1] = v.y; T[r][c4+2] = v.z; T[r][c4+3] = v.w;
    __syncthreads();
    union { bf16 h[4]; uint2 u; } o;
    #pragma unroll
    for (int i = 0; i < 4; ++i) o.h[i] = __float2bfloat16(T[c4 + i][r]);
    const int n = n0 + r;
    size_t bo = (size_t)n * (size_t)K * 2 + ((unsigned)((k0 + c4) * 2) ^ ((n & 3) << 4));
    *(uint2*)((char*)Wt + bo) = o.u;
}

// ---------------- pack x fp32 -> bf16, PRE-SWIZZLED (rows of 2048) ----------
__global__ __launch_bounds__(256) void pack_bf16(
    const float* __restrict__ src, bf16* __restrict__ dst)
{
    const size_t i = ((size_t)blockIdx.x * 256 + threadIdx.x) * 8;
    cv8 c = cvt8(*(const float4*)(src + i), *(const float4*)(src + i + 4));
    size_t bo = i * 2;                       // 16B aligned; row = bo>>12 (4096B rows)
    bo ^= (size_t)(((bo >> 12) & 3) << 4);
    *(uint4*)((char*)dst + bo) = c.u;
}

// ---- fused RoPE(K) + pack K -> [b,h,s,hd] bf16 PRE-SWIZZLED; K fp32 in-place
__global__ __launch_bounds__(256) void rope_pack_k(
    float* __restrict__ k, bf16* __restrict__ kbb,
    const float* __restrict__ cf, const float* __restrict__ sf,
    const int* __restrict__ pos)
{
    const int idx = blockIdx.x * 256 + threadIdx.x;   // B*S*H*8
    const int dg = idx & 7;                 // 8-wide group in low half
    const int h  = (idx >> 3) & (H_-1);
    const int bs = idx >> 7;
    const int s  = bs & (S_-1);
    const int b  = bs >> 11;
    const int p  = pos[bs];
    const size_t base = (size_t)bs * D_ + h*HD_ + dg*8;
    float lo[8], hi[8], c1[8], s1[8], c2[8], s2[8];
    *(float4*)&lo[0] = *(const float4*)&k[base];
    *(float4*)&lo[4] = *(const float4*)&k[base + 4];
    *(float4*)&hi[0] = *(const float4*)&k[base + 64];
    *(float4*)&hi[4] = *(const float4*)&k[base + 68];
    const float* cp = cf + (size_t)p*HD_ + dg*8;
    const float* sp = sf + (size_t)p*HD_ + dg*8;
    *(float4*)&c1[0] = *(const float4*)cp;        *(float4*)&c1[4] = *(const float4*)(cp + 4);
    *(float4*)&s1[0] = *(const float4*)sp;        *(float4*)&s1[4] = *(const float4*)(sp + 4);
    *(float4*)&c2[0] = *(const float4*)(cp + 64); *(float4*)&c2[4] = *(const float4*)(cp + 68);
    *(float4*)&s2[0] = *(const float4*)(sp + 64); *(float4*)&s2[4] = *(const float4*)(sp + 68);
    float nl[8], nh[8];
    #pragma unroll
    for (int j = 0; j < 8; ++j) {
        nl[j] = lo[j]*c1[j] - hi[j]*s1[j];
        nh[j] = hi[j]*c2[j] + lo[j]*s2[j];
    }
    *(float4*)&k[base]      = *(float4*)&nl[0];
    *(float4*)&k[base + 4]  = *(float4*)&nl[4];
    *(float4*)&k[base + 64] = *(float4*)&nh[0];
    *(float4*)&k[base + 68] = *(float4*)&nh[4];
    cv8 clo, chi;
    #pragma unroll
    for (int j = 0; j < 8; ++j) {
        clo.h[j] = __float2bfloat16(nl[j]);
        chi.h[j] = __float2bfloat16(nh[j]);
    }
    const size_t rowb = ((size_t)(b*H_ + h)*S_ + s) * (size_t)(HD_*2);
    *(uint4*)((char*)kbb + rowb + ((dg*16)       ^ ((s & 7) << 4))) = clo.u;
    *(uint4*)((char*)kbb + rowb + (((dg+8)*16)   ^ ((s & 7) << 4))) = chi.u;
}

// --- pack V^T: [b,s,h,hd] fp32 -> [b,h,hd,s] bf16, PRE-SWIZZLED 128B blocks -
// row hd: within each 128B block of the row, byte ^= ((hd&7)<<4)
__global__ __launch_bounds__(256) void pack_vt(
    const float* __restrict__ src, bf16* __restrict__ dst)
{
    __shared__ float T[32][33];
    const int s0 = blockIdx.x * 32;
    const int d0 = blockIdx.y * 32;
    const int bh = blockIdx.z;
    const int b = bh >> 4, h = bh & (H_-1);
    const int r = threadIdx.x >> 3, c4 = (threadIdx.x & 7) * 4;
    float4 v = *(const float4*)&src[((size_t)(b*S_ + s0 + r)*H_ + h)*HD_ + d0 + c4];
    T[r][c4+0] = v.x; T[r][c4+1] = v.y; T[r][c4+2] = v.z; T[r][c4+3] = v.w;
    __syncthreads();
    union { bf16 h4[4]; uint2 u; } o;
    #pragma unroll
    for (int i = 0; i < 4; ++i) o.h4[i] = __float2bfloat16(T[c4 + i][r]);
    const int hd = d0 + r;
    size_t rowb = ((size_t)bh*HD_ + hd) * (size_t)(S_*2);
    size_t colb = (size_t)(s0 + c4) * 2;
    colb = (colb & ~(size_t)127) | (((unsigned)colb & 127u) ^ (unsigned)((hd & 7) << 4));
    *(uint2*)((char*)dst + rowb + colb) = o.u;
}

// ------- fused QKV GEMM: C_which[M,2048] = A[M,K] x Wt3[6144,K] -------------
// Wt3 = concat(Wq^T, Wk^T, Wv^T) rows; global n in [0,6144). Each 128-wide
// n-tile lies inside one output tensor: which = n0g>>11, col = n0g&2047.
// Outputs are Cbase + which*BSD (Q, K, V caches). m97 structure, 1536 wgs.
__global__ __launch_bounds__(256, 3) void gemm_qkv(
    const bf16* __restrict__ A, const bf16* __restrict__ Wt,
    float* __restrict__ C, int M, int K)
{
    __shared__ __align__(16) bf16 As[128][32];   // linear, 64B rows (swizzled data)
    __shared__ __align__(16) bf16 Bs[128][32];
    const int nwg = (int)(gridDim.x * gridDim.y);
    int id = (int)(blockIdx.y * gridDim.x + blockIdx.x);
    if ((nwg & 7) == 0) id = (id & 7) * (nwg >> 3) + (id >> 3);   // XCD swizzle
    const int m0  = (id % (int)gridDim.x) * 128;
    const int n0g = (id / (int)gridDim.x) * 128;
    float* Cb = C + (size_t)(n0g >> 11) * BSD;    // which output tensor
    const int n0 = n0g & 2047;                    // column within tensor
    const int tid = threadIdx.x, lane = tid & 63, w = tid >> 6;
    const int quad = lane >> 4, l16 = lane & 15;
    const int wrow = (w >> 1) * 64, wcol = (w & 1) * 64;
    const size_t K2 = (size_t)K * 2;

    floatx4 acc[4][4] = {};

    const char* Ab = (const char*)A;
    const char* Bb = (const char*)Wt;
    char* AsB = (char*)&As[0][0];
    char* BsB = (char*)&Bs[0][0];
    const int srow = lane >> 2;              // 16 rows per 1KB issue
    const int scol = (lane & 3) * 16;

    for (int kt = 0; kt < K; kt += 32) {
        #pragma unroll
        for (int j = 0; j < 2; ++j) {
            const int row = w*32 + j*16 + srow;
            gld16(Ab + (size_t)(m0 + row)*K2 + (size_t)(kt*2) + scol,
                  AsB + w*2048 + j*1024);
            gld16(Bb + (size_t)(n0g + row)*K2 + (size_t)(kt*2) + scol,
                  BsB + w*2048 + j*1024);
        }
        __syncthreads();

        bf16x8 af[4], bfr[4];
        #pragma unroll
        for (int t = 0; t < 4; ++t) {
            const int ra = wrow + t*16 + l16;
            af[t]  = *(const bf16x8*)(AsB + ra*64 + ((quad*16) ^ ((ra & 3) << 4)));
            const int rb = wcol + t*16 + l16;
            bfr[t] = *(const bf16x8*)(BsB + rb*64 + ((quad*16) ^ ((rb & 3) << 4)));
        }
        #pragma unroll
        for (int mt = 0; mt < 4; ++mt)
            #pragma unroll
            for (int nt = 0; nt < 4; ++nt)
                acc[mt][nt] = __builtin_amdgcn_mfma_f32_16x16x32_bf16(
                    af[mt], bfr[nt], acc[mt][nt], 0, 0, 0);
        __syncthreads();
    }

    #pragma unroll
    for (int mt = 0; mt < 4; ++mt)
        #pragma unroll
        for (int nt = 0; nt < 4; ++nt)
            #pragma unroll
            for (int r = 0; r < 4; ++r)
                Cb[(size_t)(m0 + wrow + mt*16 + quad*4 + r) * 2048
                   + n0 + wcol + nt*16 + l16] = acc[mt][nt][r];
}

// ---------------- GEMM (m97 pattern): C fp32 = A bf16 x Wt bf16 -------------
__global__ __launch_bounds__(256, 3) void gemm_bb2(
    const bf16* __restrict__ A, const bf16* __restrict__ Wt,
    float* __restrict__ C, int M, int N, int K)
{
    __shared__ __align__(16) bf16 As[128][32];   // linear, 64B rows (swizzled data)
    __shared__ __align__(16) bf16 Bs[128][32];
    const int nwg = (int)(gridDim.x * gridDim.y);
    int id = (int)(blockIdx.y * gridDim.x + blockIdx.x);
    if ((nwg & 7) == 0) id = (id & 7) * (nwg >> 3) + (id >> 3);   // XCD swizzle
    const int m0 = (id % (int)gridDim.x) * 128;
    const int n0 = (id / (int)gridDim.x) * 128;
    const int tid = threadIdx.x, lane = tid & 63, w = tid >> 6;
    const int quad = lane >> 4, l16 = lane & 15;
    const int wrow = (w >> 1) * 64, wcol = (w & 1) * 64;
    const size_t K2 = (size_t)K * 2;

    floatx4 acc[4][4] = {};

    const char* Ab = (const char*)A;
    const char* Bb = (const char*)Wt;
    char* AsB = (char*)&As[0][0];
    char* BsB = (char*)&Bs[0][0];
    const int srow = lane >> 2;              // 16 rows per 1KB issue
    const int scol = (lane & 3) * 16;

    for (int kt = 0; kt < K; kt += 32) {
        #pragma unroll
        for (int j = 0; j < 2; ++j) {
            const int row = w*32 + j*16 + srow;
            gld16(Ab + (size_t)(m0 + row)*K2 + (size_t)(kt*2) + scol,
                  AsB + w*2048 + j*1024);
            gld16(Bb + (size_t)(n0 + row)*K2 + (size_t)(kt*2) + scol,
                  BsB + w*2048 + j*1024);
        }
        __syncthreads();

        bf16x8 af[4], bfr[4];
        #pragma unroll
        for (int t = 0; t < 4; ++t) {
            const int ra = wrow + t*16 + l16;
            af[t]  = *(const bf16x8*)(AsB + ra*64 + ((quad*16) ^ ((ra & 3) << 4)));
            const int rb = wcol + t*16 + l16;
            bfr[t] = *(const bf16x8*)(BsB + rb*64 + ((quad*16) ^ ((rb & 3) << 4)));
        }
        #pragma unroll
        for (int mt = 0; mt < 4; ++mt)
            #pragma unroll
            for (int nt = 0; nt < 4; ++nt)
                acc[mt][nt] = __builtin_amdgcn_mfma_f32_16x16x32_bf16(
                    af[mt], bfr[nt], acc[mt][nt], 0, 0, 0);
        __syncthreads();
    }

    #pragma unroll
    for (int mt = 0; mt < 4; ++mt)
        #pragma unroll
        for (int nt = 0; nt < 4; ++nt)
            #pragma unroll
            for (int r = 0; r < 4; ++r)
                C[(size_t)(m0 + wrow + mt*16 + quad*4 + r) * N
                  + n0 + wcol + nt*16 + l16] = acc[mt][nt][r];
}

// ---------------- GEMM v2 (fallback): A fp32, Wt bf16 (unswizzled) ----------
__global__ __launch_bounds__(256) void gemm_xw(
    const float* __restrict__ A, const bf16* __restrict__ Wt,
    float* __restrict__ C, int M, int N, int K)
{
    __shared__ __align__(16) bf16 As[128][40];
    __shared__ __align__(16) bf16 Bs[128][40];
    const int m0 = blockIdx.x * 128, n0 = blockIdx.y * 128;
    const int tid = threadIdx.x, lane = tid & 63, w = tid >> 6;
    const int quad = lane >> 4, l16 = lane & 15;
    const int wrow = (w >> 1) * 64, wcol = (w & 1) * 64;
    floatx4 acc[4][4] = {};
    const int arow = tid >> 2;
    const int acol = (tid & 3) * 8;
    for (int kt = 0; kt < K; kt += 32) {
        #pragma unroll
        for (int p = 0; p < 2; ++p) {
            const int r = p*64 + arow;
            const float* ap = &A[(size_t)(m0 + r) * K + kt + acol];
            cv8 ca = cvt8(*(const float4*)ap, *(const float4*)(ap + 4));
            *(uint4*)&As[r][acol] = ca.u;
            const bf16* bp = &Wt[(size_t)(n0 + r) * K + kt + acol];
            *(uint4*)&Bs[r][acol] = *(const uint4*)bp;
        }
        __syncthreads();
        bf16x8 af[4], bfr[4];
        #pragma unroll
        for (int t = 0; t < 4; ++t) {
            af[t]  = *(const bf16x8*)&As[wrow + t*16 + l16][quad*8];
            bfr[t] = *(const bf16x8*)&Bs[wcol + t*16 + l16][quad*8];
        }
        #pragma unroll
        for (int mt = 0; mt < 4; ++mt)
            #pragma unroll
            for (int nt = 0; nt < 4; ++nt)
                acc[mt][nt] = __builtin_amdgcn_mfma_f32_16x16x32_bf16(
                    af[mt], bfr[nt], acc[mt][nt], 0, 0, 0);
        __syncthreads();
    }
    #pragma unroll
    for (int mt = 0; mt < 4; ++mt)
        #pragma unroll
        for (int nt = 0; nt < 4; ++nt)
            #pragma unroll
            for (int r = 0; r < 4; ++r)
                C[(size_t)(m0 + wrow + mt*16 + quad*4 + r) * N
                  + n0 + wcol + nt*16 + l16] = acc[mt][nt][r];
}

// ---------------- GEMM v1 (fallback, small ws): inline W transpose ----------
__global__ __launch_bounds__(256) void gemm_f32(
    const float* __restrict__ A, const float* __restrict__ W,
    float* __restrict__ C, int M, int N, int K)
{
    __shared__ __align__(16) bf16 As[64][40];
    __shared__ __align__(16) bf16 Bs[64][40];
    const int m0 = blockIdx.x * 64, n0 = blockIdx.y * 64;
    const int tid = threadIdx.x, lane = tid & 63, w = tid >> 6;
    const int quad = lane >> 4, l16 = lane & 15;
    const int wrow = (w >> 1) * 32, wcol = (w & 1) * 32;
    floatx4 acc[2][2] = {};
    const int ar = tid >> 2, ac = (tid & 3) * 8;
    const int br = tid >> 3, bc = (tid & 7) * 8;
    for (int kt = 0; kt < K; kt += 32) {
        {
            const float* ap = &A[(size_t)(m0 + ar) * K + kt + ac];
            cv8 c = cvt8(*(const float4*)ap, *(const float4*)(ap + 4));
            *(uint4*)&As[ar][ac] = c.u;
        }
        {
            const float* wp = &W[(size_t)(kt + br) * N + n0 + bc];
            cv8 c = cvt8(*(const float4*)wp, *(const float4*)(wp + 4));
            #pragma unroll
            for (int i = 0; i < 8; ++i) Bs[bc + i][br] = c.h[i];
        }
        __syncthreads();
        bf16x8 af[2], bfr[2];
        #pragma unroll
        for (int t = 0; t < 2; ++t) {
            af[t]  = *(const bf16x8*)&As[wrow + t*16 + l16][quad*8];
            bfr[t] = *(const bf16x8*)&Bs[wcol + t*16 + l16][quad*8];
        }
        #pragma unroll
        for (int mt = 0; mt < 2; ++mt)
            #pragma unroll
            for (int nt = 0; nt < 2; ++nt)
                acc[mt][nt] = __builtin_amdgcn_mfma_f32_16x16x32_bf16(
                    af[mt], bfr[nt], acc[mt][nt], 0, 0, 0);
        __syncthreads();
    }
    #pragma unroll
    for (int mt = 0; mt < 2; ++mt)
        #pragma unroll
        for (int nt = 0; nt < 2; ++nt)
            #pragma unroll
            for (int r = 0; r < 4; ++r)
                C[(size_t)(m0 + wrow + mt*16 + quad*4 + r) * N
                  + n0 + wcol + nt*16 + l16] = acc[mt][nt][r];
}

// ---------------- RoPE q+k (fallback paths) ---------------------------------
__global__ __launch_bounds__(256) void rope_kernel(
    float* __restrict__ q, float* __restrict__ k,
    const float* __restrict__ cf, const float* __restrict__ sf,
    const int* __restrict__ pos)
{
    const int PAIRS = B_*S_*H_*(HD_/2);
    int idx = blockIdx.x * 256 + threadIdx.x;
    float* t = q;
    if (idx >= PAIRS) { t = k; idx -= PAIRS; }
    const int d  = idx & 63;
    const int h  = (idx >> 6) & (H_-1);
    const int bs = idx >> 10;
    const int p  = pos[bs];
    const float c1 = cf[p*HD_ + d],      s1 = sf[p*HD_ + d];
    const float c2 = cf[p*HD_ + d + 64], s2 = sf[p*HD_ + d + 64];
    const size_t base = (size_t)bs * D_ + h*HD_ + d;
    const float t1 = t[base], t2 = t[base + 64];
    t[base]      = t1*c1 - t2*s1;
    t[base + 64] = t2*c2 + t1*s2;
}

// ---------------- Flash attention v6: swapped-QK in-register softmax --------
// mfma(K,Q) -> S^T fragment: each lane owns q-row = l16, kcols = c*16+quad*4+r.
// Softmax is per-lane (scalar m/l state, 2 shfl_xor reduce). P is repacked to
// the PV A-fragment with 16 shfls; no Ps LDS buffer -> 48KB LDS, 3 blocks/CU.
// K double-buffered, V single-buffered (v4-proven barrier schedule).
__global__ __launch_bounds__(256, 3) void flash_attn_v6(
    const float* __restrict__ qg, const bf16* __restrict__ kb,
    const bf16* __restrict__ vb, bf16* __restrict__ ob,
    const float* __restrict__ cf, const float* __restrict__ sf,
    const int* __restrict__ pos)
{
    __shared__ __align__(16) bf16 Ks[2][64][128];   // 32KB dbuf, swizzled rows
    __shared__ __align__(16) bf16 Vt[128][64];      // 16KB single, swizzled

    const int qi = (int)gridDim.x - 1 - (int)blockIdx.x;  // heavy tiles first
    const int q0 = qi * 64;
    const int bh = blockIdx.y;
    const int b = bh >> 4, h = bh & (H_-1);
    const int tid = threadIdx.x, lane = tid & 63, w = tid >> 6;
    const int quad = lane >> 4, l16 = lane & 15;

    const char* kbase = (const char*)(kb + (size_t)bh * S_ * HD_);
    const char* vbase = (const char*)(vb + (size_t)bh * HD_ * S_);
    char* ksd = (char*)&Ks[0][0][0];
    char* vtd = (char*)&Vt[0][0];

    const int klofs = w*4096;                 // wave chunk in 16KB K tile
    const int vrow0 = w*32 + (lane >> 3);     // V^T staging row
    const int vcb   = (lane & 7) * 16;

    // prologue: stage K(0) into buffer 0 (DMA overlaps Q-RoPE below)
    #pragma unroll
    for (int j = 0; j < 4; ++j)
        gld16(kbase + klofs + j*1024 + lane*16, ksd + klofs + j*1024);

    // Q load + fused RoPE + bf16 convert (fragment: [row=l16][k=quad*8+j])
    const int qrow = q0 + w*16 + l16;
    const float* qptr = qg + ((size_t)(b*S_ + qrow))*D_ + h*HD_;
    float rq[4][8];
    #pragma unroll
    for (int c = 0; c < 4; ++c) {
        const float* qp = qptr + c*32 + quad*8;
        *(float4*)&rq[c][0] = *(const float4*)qp;
        *(float4*)&rq[c][4] = *(const float4*)(qp + 4);
    }
    const int p = pos[b*S_ + qrow];
    bf16x8 qf[4];
    #pragma unroll
    for (int c = 0; c < 4; ++c) {
        const float* cp = cf + (size_t)p*HD_ + c*32 + quad*8;
        const float* sp = sf + (size_t)p*HD_ + c*32 + quad*8;
        float cc[8], ss[8];
        *(float4*)&cc[0] = *(const float4*)cp; *(float4*)&cc[4] = *(const float4*)(cp+4);
        *(float4*)&ss[0] = *(const float4*)sp; *(float4*)&ss[4] = *(const float4*)(sp+4);
        cv8 cv;
        #pragma unroll
        for (int j = 0; j < 8; ++j) {
            const float o = (c < 2) ? rq[c][j]*cc[j] - rq[c^2][j]*ss[j]
                                    : rq[c][j]*cc[j] + rq[c^2][j]*ss[j];
            cv.h[j] = __float2bfloat16(o);
        }
        qf[c] = cv.v;
    }

    floatx4 acc_o[8] = {};
    float m_run = -30000.0f, l_run = 0.0f;    // per-lane: q-row = l16
    const int qr_sm = q0 + w*16 + l16;
    const float SCL = 0.08838834764831845f;

    __syncthreads();   // K(0) resident & visible

    for (int kt = 0; kt <= qi; ++kt) {
        const int cur = kt & 1;
        const char* ksb = ksd + cur*16384;

        if (kt < qi) {   // prefetch next K tile into other buffer
            const char* ksrc = kbase + (size_t)(kt+1)*16384;
            char* kdst = ksd + (cur^1)*16384;
            #pragma unroll
            for (int j = 0; j < 4; ++j)
                gld16(ksrc + klofs + j*1024 + lane*16, kdst + klofs + j*1024);
        }
        {   // stage V(kt) (read only after mid-barrier)
            const char* vsrc = vbase + (size_t)kt*128;
            #pragma unroll
            for (int j = 0; j < 4; ++j)
                gld16(vsrc + (size_t)(vrow0 + j*8)*(S_*2) + vcb,
                      vtd + w*4096 + j*1024);
        }

        // S^T = K Q^T : lane holds S[qrow=l16][kcol=c*16+quad*4+r]
        floatx4 sc[4] = {};
        __builtin_amdgcn_s_setprio(1);
        #pragma unroll
        for (int c = 0; c < 4; ++c)
            #pragma unroll
            for (int kc = 0; kc < 4; ++kc) {
                bf16x8 kf = *(const bf16x8*)(ksb + (c*16 + l16)*256
                              + ((kc*64 + quad*16) ^ ((l16 & 7) << 4)));
                sc[c] = __builtin_amdgcn_mfma_f32_16x16x32_bf16(kf, qf[kc], sc[c], 0, 0, 0);
            }
        __builtin_amdgcn_s_setprio(0);

        // per-lane online softmax (row = l16); reduce across the 4 quads only
        const int k0 = kt * 64;
        float pv[4][4], mt = -30000.0f;
        #pragma unroll
        for (int c = 0; c < 4; ++c)
            #pragma unroll
            for (int r = 0; r < 4; ++r) {
                const int kcol = k0 + c*16 + quad*4 + r;
                float s = sc[c][r] * SCL;
                if (kcol > qr_sm) s = -30000.0f;
                pv[c][r] = s;
                mt = fmaxf(mt, s);
            }
        mt = fmaxf(mt, __shfl_xor(mt, 16, 64));
        mt = fmaxf(mt, __shfl_xor(mt, 32, 64));
        const float mn = fmaxf(m_run, mt);
        const float alpha = __expf(m_run - mn);
        m_run = mn;
        float sum = 0.0f;
        #pragma unroll
        for (int c = 0; c < 4; ++c)
            #pragma unroll
            for (int r = 0; r < 4; ++r) {
                pv[c][r] = __expf(pv[c][r] - mn);
                sum += pv[c][r];
            }
        sum += __shfl_xor(sum, 16, 64);
        sum += __shfl_xor(sum, 32, 64);
        l_run = l_run * alpha + sum;

        // rescale O: alpha lives at lane l16=qrow; acc rows are quad*4+r
        float at[4];
        #pragma unroll
        for (int r = 0; r < 4; ++r) at[r] = __shfl(alpha, quad*4 + r, 64);
        #pragma unroll
        for (int n = 0; n < 8; ++n)
            #pragma unroll
            for (int r = 0; r < 4; ++r)
                acc_o[n][r] *= at[r];

        // pack P to bf16 pairs: pk[c][p2] = (pv[c][2p2], pv[c][2p2+1])
        unsigned pk[4][2];
        #pragma unroll
        for (int c = 0; c < 4; ++c) {
            union { bf16 h2[2]; unsigned u; } a0, a1;
            a0.h2[0] = __float2bfloat16(pv[c][0]); a0.h2[1] = __float2bfloat16(pv[c][1]);
            a1.h2[0] = __float2bfloat16(pv[c][2]); a1.h2[1] = __float2bfloat16(pv[c][3]);
            pk[c][0] = a0.u; pk[c][1] = a1.u;
        }
        // build PV A-fragments: word u of pf[kc2] holds k = kc2*32+quad*8+2u+{0,1}
        //   = source (c_src = kc2*2 + (quad>>1), quad_src = (quad&1)*2 + (u>>1),
        //      pair = u&1) at lane quad_src*16 + l16
        bf16x8 pf[2];
        #pragma unroll
        for (int kc2 = 0; kc2 < 2; ++kc2) {
            union { unsigned u[4]; bf16x8 v; } wv;
            #pragma unroll
            for (int u_ = 0; u_ < 4; ++u_) {
                const int sl = ((quad & 1)*2 + (u_ >> 1))*16 + l16;
                const unsigned w0 = __shfl(pk[kc2*2 + 0][u_ & 1], sl, 64);
                const unsigned w1 = __shfl(pk[kc2*2 + 1][u_ & 1], sl, 64);
                wv.u[u_] = (quad >> 1) ? w1 : w0;
            }
            pf[kc2] = wv.v;
        }

        __syncthreads();   // drains V(kt) + K(kt+1) DMAs; fences buffers

        __builtin_amdgcn_s_setprio(1);
        #pragma unroll
        for (int n = 0; n < 8; ++n)
            #pragma unroll
            for (int kc2 = 0; kc2 < 2; ++kc2) {
                bf16x8 vf = *(const bf16x8*)(vtd + (n*16 + l16)*128
                               + ((kc2*64 + quad*16) ^ ((l16 & 7) << 4)));
                acc_o[n] = __builtin_amdgcn_mfma_f32_16x16x32_bf16(pf[kc2], vf, acc_o[n], 0, 0, 0);
            }
        __builtin_amdgcn_s_setprio(0);

        __syncthreads();   // PV reads done before next iter's staging writes
    }

    const float linv = 1.0f / l_run;
    float lt[4];
    #pragma unroll
    for (int r = 0; r < 4; ++r) lt[r] = __shfl(linv, quad*4 + r, 64);
    #pragma unroll
    for (int n = 0; n < 8; ++n)
        #pragma unroll
        for (int r = 0; r < 4; ++r) {
            const int qr = q0 + w*16 + quad*4 + r;
            // pre-swizzled for gemm A-read: byte ^= ((m&3)<<4), m&3 == r
            size_t bo = ((((size_t)(b*S_ + qr))*D_ + h*HD_ + n*16 + l16) * 2)
                        ^ (size_t)(r << 4);
            *(bf16*)((char*)ob + bo) = __float2bfloat16(acc_o[n][r] * lt[r]);
        }
}

// ---------------- Flash attention v2 (fallback, fp32 K/V) -------------------
__global__ __launch_bounds__(256) void flash_attn(
    const float* qg, const float* __restrict__ kg,
    const float* __restrict__ vg, float* og)
{
    __shared__ __align__(16) bf16 Ks[64][136];
    __shared__ __align__(16) bf16 Vt[128][72];
    __shared__ __align__(16) bf16 Ps[4][16][72];

    const int qi = (int)gridDim.x - 1 - (int)blockIdx.x;
    const int q0 = qi * 64;
    const int bh = blockIdx.y;
    const int b = bh >> 4, h = bh & (H_-1);
    const int tid = threadIdx.x, lane = tid & 63, w = tid >> 6;
    const int quad = lane >> 4, l16 = lane & 15;

    const int qrow = q0 + w*16 + l16;
    const float* qptr = qg + ((size_t)(b*S_ + qrow)*H_ + h)*HD_;
    bf16x8 qf[4];
    #pragma unroll
    for (int c = 0; c < 4; ++c) {
        const float* qp = qptr + c*32 + quad*8;
        cv8 cv = cvt8(*(const float4*)qp, *(const float4*)(qp + 4));
        qf[c] = cv.v;
    }

    floatx4 acc_o[8] = {};
    float m_run[4], l_run[4];
    #pragma unroll
    for (int r = 0; r < 4; ++r) { m_run[r] = -30000.0f; l_run[r] = 0.f; }

    const int ksr = tid >> 2, kscg = (tid & 3) * 32;
    const int vk2 = (tid & 31) * 2, vf8 = (tid >> 5) * 8;

    for (int kt = 0; kt <= qi; ++kt) {
        const int k0 = kt * 64;
        {
            const float* kp = kg + ((size_t)(b*S_ + k0 + ksr)*H_ + h)*HD_ + kscg;
            #pragma unroll
            for (int j = 0; j < 4; ++j) {
                cv8 c = cvt8(*(const float4*)(kp + j*8), *(const float4*)(kp + j*8 + 4));
                *(uint4*)&Ks[ksr][kscg + j*8] = c.u;
            }
        }
        {
            #pragma unroll
            for (int pq = 0; pq < 2; ++pq) {
                const int f = vf8 + pq*64;
                const float* v0p = vg + ((size_t)(b*S_ + k0 + vk2)*H_ + h)*HD_ + f;
                const float* v1p = v0p + D_;
                cv8 c0 = cvt8(*(const float4*)v0p, *(const float4*)(v0p + 4));
                cv8 c1 = cvt8(*(const float4*)v1p, *(const float4*)(v1p + 4));
                #pragma unroll
                for (int i = 0; i < 8; ++i) {
                    union { bf16 h2[2]; unsigned u; } pk;
                    pk.h2[0] = c0.h[i]; pk.h2[1] = c1.h[i];
                    *(unsigned*)&Vt[f + i][vk2] = pk.u;
                }
            }
        }
        __syncthreads();

        floatx4 sc[4] = {};
        #pragma unroll
        for (int c = 0; c < 4; ++c)
            #pragma unroll
            for (int kc = 0; kc < 4; ++kc) {
                bf16x8 kf = *(const bf16x8*)&Ks[c*16 + l16][kc*32 + quad*8];
                sc[c] = __builtin_amdgcn_mfma_f32_16x16x32_bf16(qf[kc], kf, sc[c], 0, 0, 0);
            }

        float pv[4][4], mt_[4];
        #pragma unroll
        for (int r = 0; r < 4; ++r) mt_[r] = -30000.0f;
        #pragma unroll
        for (int c = 0; c < 4; ++c) {
            const int kcol = k0 + c*16 + l16;
            #pragma unroll
            for (int r = 0; r < 4; ++r) {
                const int qr = q0 + w*16 + quad*4 + r;
                float s = sc[c][r] * 0.08838834764831845f;
                if (kcol > qr) s = -30000.0f;
                pv[c][r] = s;
                mt_[r] = fmaxf(mt_[r], s);
            }
        }
        #pragma unroll
        for (int off = 1; off < 16; off <<= 1)
            #pragma unroll
            for (int r = 0; r < 4; ++r)
                mt_[r] = fmaxf(mt_[r], __shfl_xor(mt_[r], off, 64));
        float alpha[4];
        #pragma unroll
        for (int r = 0; r < 4; ++r) {
            float mn = fmaxf(m_run[r], mt_[r]);
            alpha[r] = __expf(m_run[r] - mn);
            m_run[r] = mn;
        }
        #pragma unroll
        for (int c = 0; c < 4; ++c)
            #pragma unroll
            for (int r = 0; r < 4; ++r)
                pv[c][r] = __expf(pv[c][r] - m_run[r]);
        #pragma unroll
        for (int r = 0; r < 4; ++r) {
            float s = pv[0][r] + pv[1][r] + pv[2][r] + pv[3][r];
            #pragma unroll
            for (int off = 1; off < 16; off <<= 1)
                s += __shfl_xor(s, off, 64);
            l_run[r] = l_run[r] * alpha[r] + s;
        }
        #pragma unroll
        for (int c = 0; c < 4; ++c)
            #pragma unroll
            for (int r = 0; r < 4; ++r)
                Ps[w][quad*4 + r][c*16 + l16] = __float2bfloat16(pv[c][r]);
        __syncthreads();

        #pragma unroll
        for (int n = 0; n < 8; ++n)
            #pragma unroll
            for (int r = 0; r < 4; ++r)
                acc_o[n][r] *= alpha[r];
        bf16x8 pf[2];
        #pragma unroll
        for (int kc2 = 0; kc2 < 2; ++kc2)
            pf[kc2] = *(const bf16x8*)&Ps[w][l16][kc2*32 + quad*8];
        #pragma unroll
        for (int n = 0; n < 8; ++n)
            #pragma unroll
            for (int kc2 = 0; kc2 < 2; ++kc2) {
                bf16x8 vf = *(const bf16x8*)&Vt[n*16 + l16][kc2*32 + quad*8];
                acc_o[n] = __builtin_amdgcn_mfma_f32_16x16x32_bf16(pf[kc2], vf, acc_o[n], 0, 0, 0);
            }
        __syncthreads();
    }

    #pragma unroll
    for (int n = 0; n < 8; ++n)
        #pragma unroll
        for (int r = 0; r < 4; ++r) {
            const int qr = q0 + w*16 + quad*4 + r;
            og[((size_t)(b*S_ + qr))*D_ + h*HD_ + n*16 + l16] = acc_o[n][r] / l_run[r];
        }
}

// ---------------------------------------------------------------------------
extern "C" void kernel_launch(void* const* d_in, const int* in_sizes, int n_in,
                              void* d_out, int out_size, void* d_ws, size_t ws_size,
                              hipStream_t stream) {
    const float* x  = (const float*)d_in[0];
    const float* cf = (const float*)d_in[1];
    const float* sf = (const float*)d_in[2];
    const float* Wq = (const float*)d_in[3];
    const float* Wk = (const float*)d_in[4];
    const float* Wv = (const float*)d_in[5];
    const float* Wo = (const float*)d_in[6];
    const int*  pos = (const int*)d_in[7];

    float* out  = (float*)d_out;        // final; interim: Q (pre-RoPE)
    float* kout = out + BSD;            // fp32 K cache output (post-RoPE)
    float* vout = out + 2*BSD;          // fp32 V cache output

    const size_t D2 = (size_t)D_ * D_;
    const size_t WT_BYTES = D2 * sizeof(bf16);                // 8 MB
    const size_t TB_BYTES = BSD * sizeof(bf16);               // 16 MB bf16 tensor
    const size_t NEED_V7  = 3*WT_BYTES + 3*TB_BYTES;          // 72 MB (obb aliases xb)
    const bool big = ws_size >= WT_BYTES + (size_t)128 * D_ * sizeof(float);

    if (ws_size >= NEED_V7) {
        bf16* wt3 = (bf16*)d_ws;              // 3 transposed weights, 24 MB
        bf16* xb  = wt3 + 3*D2;               // x bf16 (pre-swizzled); obb later
        bf16* kbb = xb + BSD;                 // K bf16 [b,h,s,hd] (pre-swizzled)
        bf16* vbb = kbb + BSD;                // V^T bf16 [b,h,hd,s] (pre-swizzled)
        bf16* obb = xb;                       // attn-out aliases xb (xb dead by then)

        dim3 tg(D_/32, D_/32);
        pack_bf16<<<(int)(BSD/8/256), 256, 0, stream>>>(x, xb);
        transpose_w_s<<<tg, 256, 0, stream>>>(Wq, wt3,        D_, D_);
        transpose_w_s<<<tg, 256, 0, stream>>>(Wk, wt3 + D2,   D_, D_);
        transpose_w_s<<<tg, 256, 0, stream>>>(Wv, wt3 + 2*D2, D_, D_);
        gemm_qkv<<<dim3(M_/128, (3*D_)/128), 256, 0, stream>>>(xb, wt3, out, M_, D_);
        rope_pack_k<<<(B_*S_*H_*8)/256, 256, 0, stream>>>(kout, kbb, cf, sf, pos);
        pack_vt<<<dim3(S_/32, HD_/32, B_*H_), 256, 0, stream>>>(vout, vbb);
        flash_attn_v6<<<dim3(S_/64, B_*H_), 256, 0, stream>>>(out, kbb, vbb, obb,
                                                              cf, sf, pos);
        transpose_w_s<<<tg, 256, 0, stream>>>(Wo, wt3, D_, D_);
        gemm_bb2<<<dim3(M_/128, D_/128), 256, 0, stream>>>(obb, wt3, out, M_, D_, D_);
    } else if (big) {
        bf16*  wt  = (bf16*)d_ws;
        float* cws = (float*)((char*)d_ws + WT_BYTES);
        const size_t crem = ws_size - WT_BYTES;
        dim3 tg(D_/32, D_/32), gg(M_/128, D_/128);
        transpose_w<<<tg, 256, 0, stream>>>(Wq, wt, D_, D_);
        gemm_xw<<<gg, 256, 0, stream>>>(x, wt, out,  M_, D_, D_);
        transpose_w<<<tg, 256, 0, stream>>>(Wk, wt, D_, D_);
        gemm_xw<<<gg, 256, 0, stream>>>(x, wt, kout, M_, D_, D_);
        transpose_w<<<tg, 256, 0, stream>>>(Wv, wt, D_, D_);
        gemm_xw<<<gg, 256, 0, stream>>>(x, wt, vout, M_, D_, D_);
        rope_kernel<<<(2*B_*S_*H_*(HD_/2))/256, 256, 0, stream>>>(out, kout, cf, sf, pos);
        flash_attn<<<dim3(S_/64, B_*H_), 256, 0, stream>>>(out, kout, vout, out);
        transpose_w<<<tg, 256, 0, stream>>>(Wo, wt, D_, D_);
        int R = 128;
        while (R < M_ && (size_t)(2*R) * D_ * sizeof(float) <= crem) R *= 2;
        for (int m0 = 0; m0 < M_; m0 += R) {
            gemm_xw<<<dim3(R/128, D_/128), 256, 0, stream>>>(out + (size_t)m0*D_, wt, cws, R, D_, D_);
            hipMemcpyAsync(out + (size_t)m0*D_, cws, (size_t)R*D_*sizeof(float),
                           hipMemcpyDeviceToDevice, stream);
        }
    } else {
        float* wsb = (float*)d_ws;
        dim3 gg(M_/64, D_/64);
        gemm_f32<<<gg, 256, 0, stream>>>(x, Wq, out,  M_, D_, D_);
        gemm_f32<<<gg, 256, 0, stream>>>(x, Wk, kout, M_, D_, D_);
        gemm_f32<<<gg, 256, 0, stream>>>(x, Wv, vout, M_, D_, D_);
        rope_kernel<<<(2*B_*S_*H_*(HD_/2))/256, 256, 0, stream>>>(out, kout, cf, sf, pos);
        flash_attn<<<dim3(S_/64, B_*H_), 256, 0, stream>>>(out, kout, vout, out);
        int R = 64;
        while (R < M_ && (size_t)(2*R) * D_ * sizeof(float) <= ws_size) R *= 2;
        if ((size_t)R * D_ * sizeof(float) > ws_size) R = 64;
        for (int m0 = 0; m0 < M_; m0 += R) {
            gemm_f32<<<dim3(R/64, D_/64), 256, 0, stream>>>(out + (size_t)m0*D_, Wo, wsb, R, D_, D_);
            hipMemcpyAsync(out + (size_t)m0*D_, wsb, (size_t)R*D_*sizeof(float),
                           hipMemcpyDeviceToDevice, stream);
        }
    }
}

// Round 8
// 506.228 us; speedup vs baseline: 1.1707x; 1.0516x over previous
//
#include <hip/hip_runtime.h>
#include <hip/hip_bf16.h>

#define B_ 2
#define S_ 2048
#define D_ 2048
#define H_ 16
#define HD_ 128
#define M_ (B_*S_)                 // 4096
#define BSD ((size_t)B_*S_*D_)     // 8388608 elements per output tensor

typedef short bf16x8 __attribute__((ext_vector_type(8)));   // 8 bf16 = 4 VGPRs
typedef float floatx4 __attribute__((ext_vector_type(4)));
typedef __hip_bfloat16 bf16;

union cv8 { bf16 h[8]; uint4 u; bf16x8 v; };

__device__ inline cv8 cvt8(const float4 a, const float4 b) {
    cv8 c;
    c.h[0] = __float2bfloat16(a.x); c.h[1] = __float2bfloat16(a.y);
    c.h[2] = __float2bfloat16(a.z); c.h[3] = __float2bfloat16(a.w);
    c.h[4] = __float2bfloat16(b.x); c.h[5] = __float2bfloat16(b.y);
    c.h[6] = __float2bfloat16(b.z); c.h[7] = __float2bfloat16(b.w);
    return c;
}

// async global->LDS, 16B per lane; lds dst = wave-uniform base + lane*16
__device__ __forceinline__ void gld16(const void* g, void* l) {
    __builtin_amdgcn_global_load_lds(
        (const __attribute__((address_space(1))) unsigned int*)g,
        (__attribute__((address_space(3))) unsigned int*)l,
        16, 0, 0);
}

// ---------------- W transpose+convert (plain, for fallback) -----------------
__global__ __launch_bounds__(256) void transpose_w(
    const float* __restrict__ W, bf16* __restrict__ Wt, int N, int K)
{
    __shared__ float T[32][33];
    const int k0 = blockIdx.x * 32, n0 = blockIdx.y * 32;
    const int r = threadIdx.x >> 3, c4 = (threadIdx.x & 7) * 4;
    float4 v = *(const float4*)&W[(size_t)(k0 + r) * N + n0 + c4];
    T[r][c4+0] = v.x; T[r][c4+1] = v.y; T[r][c4+2] = v.z; T[r][c4+3] = v.w;
    __syncthreads();
    union { bf16 h[4]; uint2 u; } o;
    #pragma unroll
    for (int i = 0; i < 4; ++i) o.h[i] = __float2bfloat16(T[c4 + i][r]);
    *(uint2*)&Wt[(size_t)(n0 + r) * K + k0 + c4] = o.u;
}

// ---------------- W transpose+convert, PRE-SWIZZLED rows --------------------
// Wt row n (4096B): within each 64B chunk, byte ^= ((n&3)<<4).
__global__ __launch_bounds__(256) void transpose_w_s(
    const float* __restrict__ W, bf16* __restrict__ Wt, int N, int K)
{
    __shared__ float T[32][33];
    const int k0 = blockIdx.x * 32, n0 = blockIdx.y * 32;
    const int r = threadIdx.x >> 3, c4 = (threadIdx.x & 7) * 4;
    float4 v = *(const float4*)&W[(size_t)(k0 + r) * N + n0 + c4];
    T[r][c4+0] = v.x; T[r][c4+1] = v.y; T[r][c4+2] = v.z; T[r][c4+3] = v.w;
    __syncthreads();
    union { bf16 h[4]; uint2 u; } o;
    #pragma unroll
    for (int i = 0; i < 4; ++i) o.h[i] = __float2bfloat16(T[c4 + i][r]);
    const int n = n0 + r;
    size_t bo = (size_t)n * (size_t)K * 2 + ((unsigned)((k0 + c4) * 2) ^ ((n & 3) << 4));
    *(uint2*)((char*)Wt + bo) = o.u;
}

// ---------------- pack x fp32 -> bf16, PRE-SWIZZLED (rows of 2048) ----------
__global__ __launch_bounds__(256) void pack_bf16(
    const float* __restrict__ src, bf16* __restrict__ dst)
{
    const size_t i = ((size_t)blockIdx.x * 256 + threadIdx.x) * 8;
    cv8 c = cvt8(*(const float4*)(src + i), *(const float4*)(src + i + 4));
    size_t bo = i * 2;                       // 16B aligned; row = bo>>12 (4096B rows)
    bo ^= (size_t)(((bo >> 12) & 3) << 4);
    *(uint4*)((char*)dst + bo) = c.u;
}

// ---- fused RoPE(K) + pack K -> [b,h,s,hd] bf16 PRE-SWIZZLED; K fp32 in-place
__global__ __launch_bounds__(256) void rope_pack_k(
    float* __restrict__ k, bf16* __restrict__ kbb,
    const float* __restrict__ cf, const float* __restrict__ sf,
    const int* __restrict__ pos)
{
    const int idx = blockIdx.x * 256 + threadIdx.x;   // B*S*H*8
    const int dg = idx & 7;                 // 8-wide group in low half
    const int h  = (idx >> 3) & (H_-1);
    const int bs = idx >> 7;
    const int s  = bs & (S_-1);
    const int b  = bs >> 11;
    const int p  = pos[bs];
    const size_t base = (size_t)bs * D_ + h*HD_ + dg*8;
    float lo[8], hi[8], c1[8], s1[8], c2[8], s2[8];
    *(float4*)&lo[0] = *(const float4*)&k[base];
    *(float4*)&lo[4] = *(const float4*)&k[base + 4];
    *(float4*)&hi[0] = *(const float4*)&k[base + 64];
    *(float4*)&hi[4] = *(const float4*)&k[base + 68];
    const float* cp = cf + (size_t)p*HD_ + dg*8;
    const float* sp = sf + (size_t)p*HD_ + dg*8;
    *(float4*)&c1[0] = *(const float4*)cp;        *(float4*)&c1[4] = *(const float4*)(cp + 4);
    *(float4*)&s1[0] = *(const float4*)sp;        *(float4*)&s1[4] = *(const float4*)(sp + 4);
    *(float4*)&c2[0] = *(const float4*)(cp + 64); *(float4*)&c2[4] = *(const float4*)(cp + 68);
    *(float4*)&s2[0] = *(const float4*)(sp + 64); *(float4*)&s2[4] = *(const float4*)(sp + 68);
    float nl[8], nh[8];
    #pragma unroll
    for (int j = 0; j < 8; ++j) {
        nl[j] = lo[j]*c1[j] - hi[j]*s1[j];
        nh[j] = hi[j]*c2[j] + lo[j]*s2[j];
    }
    *(float4*)&k[base]      = *(float4*)&nl[0];
    *(float4*)&k[base + 4]  = *(float4*)&nl[4];
    *(float4*)&k[base + 64] = *(float4*)&nh[0];
    *(float4*)&k[base + 68] = *(float4*)&nh[4];
    cv8 clo, chi;
    #pragma unroll
    for (int j = 0; j < 8; ++j) {
        clo.h[j] = __float2bfloat16(nl[j]);
        chi.h[j] = __float2bfloat16(nh[j]);
    }
    const size_t rowb = ((size_t)(b*H_ + h)*S_ + s) * (size_t)(HD_*2);
    *(uint4*)((char*)kbb + rowb + ((dg*16)       ^ ((s & 7) << 4))) = clo.u;
    *(uint4*)((char*)kbb + rowb + (((dg+8)*16)   ^ ((s & 7) << 4))) = chi.u;
}

// --- pack V^T: [b,s,h,hd] fp32 -> [b,h,hd,s] bf16, PRE-SWIZZLED 128B blocks -
// row hd: within each 128B block of the row, byte ^= ((hd&7)<<4)
__global__ __launch_bounds__(256) void pack_vt(
    const float* __restrict__ src, bf16* __restrict__ dst)
{
    __shared__ float T[32][33];
    const int s0 = blockIdx.x * 32;
    const int d0 = blockIdx.y * 32;
    const int bh = blockIdx.z;
    const int b = bh >> 4, h = bh & (H_-1);
    const int r = threadIdx.x >> 3, c4 = (threadIdx.x & 7) * 4;
    float4 v = *(const float4*)&src[((size_t)(b*S_ + s0 + r)*H_ + h)*HD_ + d0 + c4];
    T[r][c4+0] = v.x; T[r][c4+1] = v.y; T[r][c4+2] = v.z; T[r][c4+3] = v.w;
    __syncthreads();
    union { bf16 h4[4]; uint2 u; } o;
    #pragma unroll
    for (int i = 0; i < 4; ++i) o.h4[i] = __float2bfloat16(T[c4 + i][r]);
    const int hd = d0 + r;
    size_t rowb = ((size_t)bh*HD_ + hd) * (size_t)(S_*2);
    size_t colb = (size_t)(s0 + c4) * 2;
    colb = (colb & ~(size_t)127) | (((unsigned)colb & 127u) ^ (unsigned)((hd & 7) << 4));
    *(uint2*)((char*)dst + rowb + colb) = o.u;
}

// ------- fused QKV GEMM: C_which[M,2048] = A[M,K] x Wt3[6144,K] -------------
__global__ __launch_bounds__(256, 3) void gemm_qkv(
    const bf16* __restrict__ A, const bf16* __restrict__ Wt,
    float* __restrict__ C, int M, int K)
{
    __shared__ __align__(16) bf16 As[128][32];   // linear, 64B rows (swizzled data)
    __shared__ __align__(16) bf16 Bs[128][32];
    const int nwg = (int)(gridDim.x * gridDim.y);
    int id = (int)(blockIdx.y * gridDim.x + blockIdx.x);
    if ((nwg & 7) == 0) id = (id & 7) * (nwg >> 3) + (id >> 3);   // XCD swizzle
    const int m0  = (id % (int)gridDim.x) * 128;
    const int n0g = (id / (int)gridDim.x) * 128;
    float* Cb = C + (size_t)(n0g >> 11) * BSD;    // which output tensor
    const int n0 = n0g & 2047;                    // column within tensor
    const int tid = threadIdx.x, lane = tid & 63, w = tid >> 6;
    const int quad = lane >> 4, l16 = lane & 15;
    const int wrow = (w >> 1) * 64, wcol = (w & 1) * 64;
    const size_t K2 = (size_t)K * 2;

    floatx4 acc[4][4] = {};

    const char* Ab = (const char*)A;
    const char* Bb = (const char*)Wt;
    char* AsB = (char*)&As[0][0];
    char* BsB = (char*)&Bs[0][0];
    const int srow = lane >> 2;              // 16 rows per 1KB issue
    const int scol = (lane & 3) * 16;

    for (int kt = 0; kt < K; kt += 32) {
        #pragma unroll
        for (int j = 0; j < 2; ++j) {
            const int row = w*32 + j*16 + srow;
            gld16(Ab + (size_t)(m0 + row)*K2 + (size_t)(kt*2) + scol,
                  AsB + w*2048 + j*1024);
            gld16(Bb + (size_t)(n0g + row)*K2 + (size_t)(kt*2) + scol,
                  BsB + w*2048 + j*1024);
        }
        __syncthreads();

        bf16x8 af[4], bfr[4];
        #pragma unroll
        for (int t = 0; t < 4; ++t) {
            const int ra = wrow + t*16 + l16;
            af[t]  = *(const bf16x8*)(AsB + ra*64 + ((quad*16) ^ ((ra & 3) << 4)));
            const int rb = wcol + t*16 + l16;
            bfr[t] = *(const bf16x8*)(BsB + rb*64 + ((quad*16) ^ ((rb & 3) << 4)));
        }
        #pragma unroll
        for (int mt = 0; mt < 4; ++mt)
            #pragma unroll
            for (int nt = 0; nt < 4; ++nt)
                acc[mt][nt] = __builtin_amdgcn_mfma_f32_16x16x32_bf16(
                    af[mt], bfr[nt], acc[mt][nt], 0, 0, 0);
        __syncthreads();
    }

    #pragma unroll
    for (int mt = 0; mt < 4; ++mt)
        #pragma unroll
        for (int nt = 0; nt < 4; ++nt)
            #pragma unroll
            for (int r = 0; r < 4; ++r)
                Cb[(size_t)(m0 + wrow + mt*16 + quad*4 + r) * 2048
                   + n0 + wcol + nt*16 + l16] = acc[mt][nt][r];
}

// ---------------- GEMM (m97 pattern): C fp32 = A bf16 x Wt bf16 -------------
__global__ __launch_bounds__(256, 3) void gemm_bb2(
    const bf16* __restrict__ A, const bf16* __restrict__ Wt,
    float* __restrict__ C, int M, int N, int K)
{
    __shared__ __align__(16) bf16 As[128][32];   // linear, 64B rows (swizzled data)
    __shared__ __align__(16) bf16 Bs[128][32];
    const int nwg = (int)(gridDim.x * gridDim.y);
    int id = (int)(blockIdx.y * gridDim.x + blockIdx.x);
    if ((nwg & 7) == 0) id = (id & 7) * (nwg >> 3) + (id >> 3);   // XCD swizzle
    const int m0 = (id % (int)gridDim.x) * 128;
    const int n0 = (id / (int)gridDim.x) * 128;
    const int tid = threadIdx.x, lane = tid & 63, w = tid >> 6;
    const int quad = lane >> 4, l16 = lane & 15;
    const int wrow = (w >> 1) * 64, wcol = (w & 1) * 64;
    const size_t K2 = (size_t)K * 2;

    floatx4 acc[4][4] = {};

    const char* Ab = (const char*)A;
    const char* Bb = (const char*)Wt;
    char* AsB = (char*)&As[0][0];
    char* BsB = (char*)&Bs[0][0];
    const int srow = lane >> 2;              // 16 rows per 1KB issue
    const int scol = (lane & 3) * 16;

    for (int kt = 0; kt < K; kt += 32) {
        #pragma unroll
        for (int j = 0; j < 2; ++j) {
            const int row = w*32 + j*16 + srow;
            gld16(Ab + (size_t)(m0 + row)*K2 + (size_t)(kt*2) + scol,
                  AsB + w*2048 + j*1024);
            gld16(Bb + (size_t)(n0 + row)*K2 + (size_t)(kt*2) + scol,
                  BsB + w*2048 + j*1024);
        }
        __syncthreads();

        bf16x8 af[4], bfr[4];
        #pragma unroll
        for (int t = 0; t < 4; ++t) {
            const int ra = wrow + t*16 + l16;
            af[t]  = *(const bf16x8*)(AsB + ra*64 + ((quad*16) ^ ((ra & 3) << 4)));
            const int rb = wcol + t*16 + l16;
            bfr[t] = *(const bf16x8*)(BsB + rb*64 + ((quad*16) ^ ((rb & 3) << 4)));
        }
        #pragma unroll
        for (int mt = 0; mt < 4; ++mt)
            #pragma unroll
            for (int nt = 0; nt < 4; ++nt)
                acc[mt][nt] = __builtin_amdgcn_mfma_f32_16x16x32_bf16(
                    af[mt], bfr[nt], acc[mt][nt], 0, 0, 0);
        __syncthreads();
    }

    #pragma unroll
    for (int mt = 0; mt < 4; ++mt)
        #pragma unroll
        for (int nt = 0; nt < 4; ++nt)
            #pragma unroll
            for (int r = 0; r < 4; ++r)
                C[(size_t)(m0 + wrow + mt*16 + quad*4 + r) * N
                  + n0 + wcol + nt*16 + l16] = acc[mt][nt][r];
}

// ---------------- GEMM v2 (fallback): A fp32, Wt bf16 (unswizzled) ----------
__global__ __launch_bounds__(256) void gemm_xw(
    const float* __restrict__ A, const bf16* __restrict__ Wt,
    float* __restrict__ C, int M, int N, int K)
{
    __shared__ __align__(16) bf16 As[128][40];
    __shared__ __align__(16) bf16 Bs[128][40];
    const int m0 = blockIdx.x * 128, n0 = blockIdx.y * 128;
    const int tid = threadIdx.x, lane = tid & 63, w = tid >> 6;
    const int quad = lane >> 4, l16 = lane & 15;
    const int wrow = (w >> 1) * 64, wcol = (w & 1) * 64;
    floatx4 acc[4][4] = {};
    const int arow = tid >> 2;
    const int acol = (tid & 3) * 8;
    for (int kt = 0; kt < K; kt += 32) {
        #pragma unroll
        for (int p = 0; p < 2; ++p) {
            const int r = p*64 + arow;
            const float* ap = &A[(size_t)(m0 + r) * K + kt + acol];
            cv8 ca = cvt8(*(const float4*)ap, *(const float4*)(ap + 4));
            *(uint4*)&As[r][acol] = ca.u;
            const bf16* bp = &Wt[(size_t)(n0 + r) * K + kt + acol];
            *(uint4*)&Bs[r][acol] = *(const uint4*)bp;
        }
        __syncthreads();
        bf16x8 af[4], bfr[4];
        #pragma unroll
        for (int t = 0; t < 4; ++t) {
            af[t]  = *(const bf16x8*)&As[wrow + t*16 + l16][quad*8];
            bfr[t] = *(const bf16x8*)&Bs[wcol + t*16 + l16][quad*8];
        }
        #pragma unroll
        for (int mt = 0; mt < 4; ++mt)
            #pragma unroll
            for (int nt = 0; nt < 4; ++nt)
                acc[mt][nt] = __builtin_amdgcn_mfma_f32_16x16x32_bf16(
                    af[mt], bfr[nt], acc[mt][nt], 0, 0, 0);
        __syncthreads();
    }
    #pragma unroll
    for (int mt = 0; mt < 4; ++mt)
        #pragma unroll
        for (int nt = 0; nt < 4; ++nt)
            #pragma unroll
            for (int r = 0; r < 4; ++r)
                C[(size_t)(m0 + wrow + mt*16 + quad*4 + r) * N
                  + n0 + wcol + nt*16 + l16] = acc[mt][nt][r];
}

// ---------------- GEMM v1 (fallback, small ws): inline W transpose ----------
__global__ __launch_bounds__(256) void gemm_f32(
    const float* __restrict__ A, const float* __restrict__ W,
    float* __restrict__ C, int M, int N, int K)
{
    __shared__ __align__(16) bf16 As[64][40];
    __shared__ __align__(16) bf16 Bs[64][40];
    const int m0 = blockIdx.x * 64, n0 = blockIdx.y * 64;
    const int tid = threadIdx.x, lane = tid & 63, w = tid >> 6;
    const int quad = lane >> 4, l16 = lane & 15;
    const int wrow = (w >> 1) * 32, wcol = (w & 1) * 32;
    floatx4 acc[2][2] = {};
    const int ar = tid >> 2, ac = (tid & 3) * 8;
    const int br = tid >> 3, bc = (tid & 7) * 8;
    for (int kt = 0; kt < K; kt += 32) {
        {
            const float* ap = &A[(size_t)(m0 + ar) * K + kt + ac];
            cv8 c = cvt8(*(const float4*)ap, *(const float4*)(ap + 4));
            *(uint4*)&As[ar][ac] = c.u;
        }
        {
            const float* wp = &W[(size_t)(kt + br) * N + n0 + bc];
            cv8 c = cvt8(*(const float4*)wp, *(const float4*)(wp + 4));
            #pragma unroll
            for (int i = 0; i < 8; ++i) Bs[bc + i][br] = c.h[i];
        }
        __syncthreads();
        bf16x8 af[2], bfr[2];
        #pragma unroll
        for (int t = 0; t < 2; ++t) {
            af[t]  = *(const bf16x8*)&As[wrow + t*16 + l16][quad*8];
            bfr[t] = *(const bf16x8*)&Bs[wcol + t*16 + l16][quad*8];
        }
        #pragma unroll
        for (int mt = 0; mt < 2; ++mt)
            #pragma unroll
            for (int nt = 0; nt < 2; ++nt)
                acc[mt][nt] = __builtin_amdgcn_mfma_f32_16x16x32_bf16(
                    af[mt], bfr[nt], acc[mt][nt], 0, 0, 0);
        __syncthreads();
    }
    #pragma unroll
    for (int mt = 0; mt < 2; ++mt)
        #pragma unroll
        for (int nt = 0; nt < 2; ++nt)
            #pragma unroll
            for (int r = 0; r < 4; ++r)
                C[(size_t)(m0 + wrow + mt*16 + quad*4 + r) * N
                  + n0 + wcol + nt*16 + l16] = acc[mt][nt][r];
}

// ---------------- RoPE q+k (fallback paths) ---------------------------------
__global__ __launch_bounds__(256) void rope_kernel(
    float* __restrict__ q, float* __restrict__ k,
    const float* __restrict__ cf, const float* __restrict__ sf,
    const int* __restrict__ pos)
{
    const int PAIRS = B_*S_*H_*(HD_/2);
    int idx = blockIdx.x * 256 + threadIdx.x;
    float* t = q;
    if (idx >= PAIRS) { t = k; idx -= PAIRS; }
    const int d  = idx & 63;
    const int h  = (idx >> 6) & (H_-1);
    const int bs = idx >> 10;
    const int p  = pos[bs];
    const float c1 = cf[p*HD_ + d],      s1 = sf[p*HD_ + d];
    const float c2 = cf[p*HD_ + d + 64], s2 = sf[p*HD_ + d + 64];
    const size_t base = (size_t)bs * D_ + h*HD_ + d;
    const float t1 = t[base], t2 = t[base + 64];
    t[base]      = t1*c1 - t2*s1;
    t[base + 64] = t2*c2 + t1*s2;
}

// ---------------- Flash attention v7: 8-wave, 128-q-row blocks --------------
// Same swapped-QK in-register softmax as v6, but 512 threads: 8 waves share
// each staged K/V tile (2x MFMA per staged byte, half the barrier-iterations),
// grid 512 blocks -> fully resident, 16+ waves/CU to overlap barrier drains.
// LDS unchanged at 48KB (K dbuf 32KB + V 16KB).
__global__ __launch_bounds__(512, 4) void flash_attn_v7(
    const float* __restrict__ qg, const bf16* __restrict__ kb,
    const bf16* __restrict__ vb, bf16* __restrict__ ob,
    const float* __restrict__ cf, const float* __restrict__ sf,
    const int* __restrict__ pos)
{
    __shared__ __align__(16) bf16 Ks[2][64][128];   // 32KB dbuf, swizzled rows
    __shared__ __align__(16) bf16 Vt[128][64];      // 16KB single, swizzled

    const int qi = (int)gridDim.x - 1 - (int)blockIdx.x;  // heavy tiles first
    const int q0 = qi * 128;
    const int ktmax = 2*qi + 1;               // k-tiles 0..ktmax (64 wide)
    const int bh = blockIdx.y;
    const int b = bh >> 4, h = bh & (H_-1);
    const int tid = threadIdx.x, lane = tid & 63, w = tid >> 6;   // w in [0,8)
    const int quad = lane >> 4, l16 = lane & 15;

    const char* kbase = (const char*)(kb + (size_t)bh * S_ * HD_);
    const char* vbase = (const char*)(vb + (size_t)bh * HD_ * S_);
    char* ksd = (char*)&Ks[0][0][0];
    char* vtd = (char*)&Vt[0][0];

    const int klofs = w*2048;                 // wave chunk in 16KB K tile
    const int vrow0 = w*16 + (lane >> 3);     // V^T staging row
    const int vcb   = (lane & 7) * 16;

    // prologue: stage K(0) into buffer 0 (DMA overlaps Q-RoPE below)
    #pragma unroll
    for (int j = 0; j < 2; ++j)
        gld16(kbase + klofs + j*1024 + lane*16, ksd + klofs + j*1024);

    // Q load + fused RoPE + bf16 convert (fragment: [row=l16][k=quad*8+j])
    const int qrow = q0 + w*16 + l16;
    const float* qptr = qg + ((size_t)(b*S_ + qrow))*D_ + h*HD_;
    float rq[4][8];
    #pragma unroll
    for (int c = 0; c < 4; ++c) {
        const float* qp = qptr + c*32 + quad*8;
        *(float4*)&rq[c][0] = *(const float4*)qp;
        *(float4*)&rq[c][4] = *(const float4*)(qp + 4);
    }
    const int p = pos[b*S_ + qrow];
    bf16x8 qf[4];
    #pragma unroll
    for (int c = 0; c < 4; ++c) {
        const float* cp = cf + (size_t)p*HD_ + c*32 + quad*8;
        const float* sp = sf + (size_t)p*HD_ + c*32 + quad*8;
        float cc[8], ss[8];
        *(float4*)&cc[0] = *(const float4*)cp; *(float4*)&cc[4] = *(const float4*)(cp+4);
        *(float4*)&ss[0] = *(const float4*)sp; *(float4*)&ss[4] = *(const float4*)(sp+4);
        cv8 cv;
        #pragma unroll
        for (int j = 0; j < 8; ++j) {
            const float o = (c < 2) ? rq[c][j]*cc[j] - rq[c^2][j]*ss[j]
                                    : rq[c][j]*cc[j] + rq[c^2][j]*ss[j];
            cv.h[j] = __float2bfloat16(o);
        }
        qf[c] = cv.v;
    }

    floatx4 acc_o[8] = {};
    float m_run = -30000.0f, l_run = 0.0f;    // per-lane: q-row = l16 group
    const int qr_sm = qrow;
    const float SCL = 0.08838834764831845f;

    __syncthreads();   // K(0) resident & visible

    for (int kt = 0; kt <= ktmax; ++kt) {
        const int cur = kt & 1;
        const char* ksb = ksd + cur*16384;

        if (kt < ktmax) {   // prefetch next K tile into other buffer
            const char* ksrc = kbase + (size_t)(kt+1)*16384;
            char* kdst = ksd + (cur^1)*16384;
            #pragma unroll
            for (int j = 0; j < 2; ++j)
                gld16(ksrc + klofs + j*1024 + lane*16, kdst + klofs + j*1024);
        }
        {   // stage V(kt) (read only after mid-barrier)
            const char* vsrc = vbase + (size_t)kt*128;
            #pragma unroll
            for (int j = 0; j < 2; ++j)
                gld16(vsrc + (size_t)(vrow0 + j*8)*(S_*2) + vcb,
                      vtd + w*2048 + j*1024);
        }

        // S^T = K Q^T : lane holds S[qrow][kcol=c*16+quad*4+r]
        floatx4 sc[4] = {};
        __builtin_amdgcn_s_setprio(1);
        #pragma unroll
        for (int c = 0; c < 4; ++c)
            #pragma unroll
            for (int kc = 0; kc < 4; ++kc) {
                bf16x8 kf = *(const bf16x8*)(ksb + (c*16 + l16)*256
                              + ((kc*64 + quad*16) ^ ((l16 & 7) << 4)));
                sc[c] = __builtin_amdgcn_mfma_f32_16x16x32_bf16(kf, qf[kc], sc[c], 0, 0, 0);
            }
        __builtin_amdgcn_s_setprio(0);

        // per-lane online softmax (row = l16 group); reduce across 4 quads
        const int k0 = kt * 64;
        float pv[4][4], mt = -30000.0f;
        #pragma unroll
        for (int c = 0; c < 4; ++c)
            #pragma unroll
            for (int r = 0; r < 4; ++r) {
                const int kcol = k0 + c*16 + quad*4 + r;
                float s = sc[c][r] * SCL;
                if (kcol > qr_sm) s = -30000.0f;
                pv[c][r] = s;
                mt = fmaxf(mt, s);
            }
        mt = fmaxf(mt, __shfl_xor(mt, 16, 64));
        mt = fmaxf(mt, __shfl_xor(mt, 32, 64));
        const float mn = fmaxf(m_run, mt);
        const float alpha = __expf(m_run - mn);
        m_run = mn;
        float sum = 0.0f;
        #pragma unroll
        for (int c = 0; c < 4; ++c)
            #pragma unroll
            for (int r = 0; r < 4; ++r) {
                pv[c][r] = __expf(pv[c][r] - mn);
                sum += pv[c][r];
            }
        sum += __shfl_xor(sum, 16, 64);
        sum += __shfl_xor(sum, 32, 64);
        l_run = l_run * alpha + sum;

        // rescale O: alpha lives at lane l16=qrow; acc rows are quad*4+r
        float at[4];
        #pragma unroll
        for (int r = 0; r < 4; ++r) at[r] = __shfl(alpha, quad*4 + r, 64);
        #pragma unroll
        for (int n = 0; n < 8; ++n)
            #pragma unroll
            for (int r = 0; r < 4; ++r)
                acc_o[n][r] *= at[r];

        // pack P to bf16 pairs: pk[c][p2] = (pv[c][2p2], pv[c][2p2+1])
        unsigned pk[4][2];
        #pragma unroll
        for (int c = 0; c < 4; ++c) {
            union { bf16 h2[2]; unsigned u; } a0, a1;
            a0.h2[0] = __float2bfloat16(pv[c][0]); a0.h2[1] = __float2bfloat16(pv[c][1]);
            a1.h2[0] = __float2bfloat16(pv[c][2]); a1.h2[1] = __float2bfloat16(pv[c][3]);
            pk[c][0] = a0.u; pk[c][1] = a1.u;
        }
        // build PV A-fragments: word u of pf[kc2] holds k = kc2*32+quad*8+2u+{0,1}
        bf16x8 pf[2];
        #pragma unroll
        for (int kc2 = 0; kc2 < 2; ++kc2) {
            union { unsigned u[4]; bf16x8 v; } wv;
            #pragma unroll
            for (int u_ = 0; u_ < 4; ++u_) {
                const int sl = ((quad & 1)*2 + (u_ >> 1))*16 + l16;
                const unsigned w0 = __shfl(pk[kc2*2 + 0][u_ & 1], sl, 64);
                const unsigned w1 = __shfl(pk[kc2*2 + 1][u_ & 1], sl, 64);
                wv.u[u_] = (quad >> 1) ? w1 : w0;
            }
            pf[kc2] = wv.v;
        }

        __syncthreads();   // drains V(kt) + K(kt+1) DMAs; fences buffers

        __builtin_amdgcn_s_setprio(1);
        #pragma unroll
        for (int n = 0; n < 8; ++n)
            #pragma unroll
            for (int kc2 = 0; kc2 < 2; ++kc2) {
                bf16x8 vf = *(const bf16x8*)(vtd + (n*16 + l16)*128
                               + ((kc2*64 + quad*16) ^ ((l16 & 7) << 4)));
                acc_o[n] = __builtin_amdgcn_mfma_f32_16x16x32_bf16(pf[kc2], vf, acc_o[n], 0, 0, 0);
            }
        __builtin_amdgcn_s_setprio(0);

        __syncthreads();   // PV reads done before next iter's staging writes
    }

    const float linv = 1.0f / l_run;
    float lt[4];
    #pragma unroll
    for (int r = 0; r < 4; ++r) lt[r] = __shfl(linv, quad*4 + r, 64);
    #pragma unroll
    for (int n = 0; n < 8; ++n)
        #pragma unroll
        for (int r = 0; r < 4; ++r) {
            const int qr = q0 + w*16 + quad*4 + r;
            // pre-swizzled for gemm A-read: byte ^= ((m&3)<<4), m&3 == r
            size_t bo = ((((size_t)(b*S_ + qr))*D_ + h*HD_ + n*16 + l16) * 2)
                        ^ (size_t)(r << 4);
            *(bf16*)((char*)ob + bo) = __float2bfloat16(acc_o[n][r] * lt[r]);
        }
}

// ---------------- Flash attention v2 (fallback, fp32 K/V) -------------------
__global__ __launch_bounds__(256) void flash_attn(
    const float* qg, const float* __restrict__ kg,
    const float* __restrict__ vg, float* og)
{
    __shared__ __align__(16) bf16 Ks[64][136];
    __shared__ __align__(16) bf16 Vt[128][72];
    __shared__ __align__(16) bf16 Ps[4][16][72];

    const int qi = (int)gridDim.x - 1 - (int)blockIdx.x;
    const int q0 = qi * 64;
    const int bh = blockIdx.y;
    const int b = bh >> 4, h = bh & (H_-1);
    const int tid = threadIdx.x, lane = tid & 63, w = tid >> 6;
    const int quad = lane >> 4, l16 = lane & 15;

    const int qrow = q0 + w*16 + l16;
    const float* qptr = qg + ((size_t)(b*S_ + qrow)*H_ + h)*HD_;
    bf16x8 qf[4];
    #pragma unroll
    for (int c = 0; c < 4; ++c) {
        const float* qp = qptr + c*32 + quad*8;
        cv8 cv = cvt8(*(const float4*)qp, *(const float4*)(qp + 4));
        qf[c] = cv.v;
    }

    floatx4 acc_o[8] = {};
    float m_run[4], l_run[4];
    #pragma unroll
    for (int r = 0; r < 4; ++r) { m_run[r] = -30000.0f; l_run[r] = 0.f; }

    const int ksr = tid >> 2, kscg = (tid & 3) * 32;
    const int vk2 = (tid & 31) * 2, vf8 = (tid >> 5) * 8;

    for (int kt = 0; kt <= qi; ++kt) {
        const int k0 = kt * 64;
        {
            const float* kp = kg + ((size_t)(b*S_ + k0 + ksr)*H_ + h)*HD_ + kscg;
            #pragma unroll
            for (int j = 0; j < 4; ++j) {
                cv8 c = cvt8(*(const float4*)(kp + j*8), *(const float4*)(kp + j*8 + 4));
                *(uint4*)&Ks[ksr][kscg + j*8] = c.u;
            }
        }
        {
            #pragma unroll
            for (int pq = 0; pq < 2; ++pq) {
                const int f = vf8 + pq*64;
                const float* v0p = vg + ((size_t)(b*S_ + k0 + vk2)*H_ + h)*HD_ + f;
                const float* v1p = v0p + D_;
                cv8 c0 = cvt8(*(const float4*)v0p, *(const float4*)(v0p + 4));
                cv8 c1 = cvt8(*(const float4*)v1p, *(const float4*)(v1p + 4));
                #pragma unroll
                for (int i = 0; i < 8; ++i) {
                    union { bf16 h2[2]; unsigned u; } pk;
                    pk.h2[0] = c0.h[i]; pk.h2[1] = c1.h[i];
                    *(unsigned*)&Vt[f + i][vk2] = pk.u;
                }
            }
        }
        __syncthreads();

        floatx4 sc[4] = {};
        #pragma unroll
        for (int c = 0; c < 4; ++c)
            #pragma unroll
            for (int kc = 0; kc < 4; ++kc) {
                bf16x8 kf = *(const bf16x8*)&Ks[c*16 + l16][kc*32 + quad*8];
                sc[c] = __builtin_amdgcn_mfma_f32_16x16x32_bf16(qf[kc], kf, sc[c], 0, 0, 0);
            }

        float pv[4][4], mt_[4];
        #pragma unroll
        for (int r = 0; r < 4; ++r) mt_[r] = -30000.0f;
        #pragma unroll
        for (int c = 0; c < 4; ++c) {
            const int kcol = k0 + c*16 + l16;
            #pragma unroll
            for (int r = 0; r < 4; ++r) {
                const int qr = q0 + w*16 + quad*4 + r;
                float s = sc[c][r] * 0.08838834764831845f;
                if (kcol > qr) s = -30000.0f;
                pv[c][r] = s;
                mt_[r] = fmaxf(mt_[r], s);
            }
        }
        #pragma unroll
        for (int off = 1; off < 16; off <<= 1)
            #pragma unroll
            for (int r = 0; r < 4; ++r)
                mt_[r] = fmaxf(mt_[r], __shfl_xor(mt_[r], off, 64));
        float alpha[4];
        #pragma unroll
        for (int r = 0; r < 4; ++r) {
            float mn = fmaxf(m_run[r], mt_[r]);
            alpha[r] = __expf(m_run[r] - mn);
            m_run[r] = mn;
        }
        #pragma unroll
        for (int c = 0; c < 4; ++c)
            #pragma unroll
            for (int r = 0; r < 4; ++r)
                pv[c][r] = __expf(pv[c][r] - m_run[r]);
        #pragma unroll
        for (int r = 0; r < 4; ++r) {
            float s = pv[0][r] + pv[1][r] + pv[2][r] + pv[3][r];
            #pragma unroll
            for (int off = 1; off < 16; off <<= 1)
                s += __shfl_xor(s, off, 64);
            l_run[r] = l_run[r] * alpha[r] + s;
        }
        #pragma unroll
        for (int c = 0; c < 4; ++c)
            #pragma unroll
            for (int r = 0; r < 4; ++r)
                Ps[w][quad*4 + r][c*16 + l16] = __float2bfloat16(pv[c][r]);
        __syncthreads();

        #pragma unroll
        for (int n = 0; n < 8; ++n)
            #pragma unroll
            for (int r = 0; r < 4; ++r)
                acc_o[n][r] *= alpha[r];
        bf16x8 pf[2];
        #pragma unroll
        for (int kc2 = 0; kc2 < 2; ++kc2)
            pf[kc2] = *(const bf16x8*)&Ps[w][l16][kc2*32 + quad*8];
        #pragma unroll
        for (int n = 0; n < 8; ++n)
            #pragma unroll
            for (int kc2 = 0; kc2 < 2; ++kc2) {
                bf16x8 vf = *(const bf16x8*)&Vt[n*16 + l16][kc2*32 + quad*8];
                acc_o[n] = __builtin_amdgcn_mfma_f32_16x16x32_bf16(pf[kc2], vf, acc_o[n], 0, 0, 0);
            }
        __syncthreads();
    }

    #pragma unroll
    for (int n = 0; n < 8; ++n)
        #pragma unroll
        for (int r = 0; r < 4; ++r) {
            const int qr = q0 + w*16 + quad*4 + r;
            og[((size_t)(b*S_ + qr))*D_ + h*HD_ + n*16 + l16] = acc_o[n][r] / l_run[r];
        }
}

// ---------------------------------------------------------------------------
extern "C" void kernel_launch(void* const* d_in, const int* in_sizes, int n_in,
                              void* d_out, int out_size, void* d_ws, size_t ws_size,
                              hipStream_t stream) {
    const float* x  = (const float*)d_in[0];
    const float* cf = (const float*)d_in[1];
    const float* sf = (const float*)d_in[2];
    const float* Wq = (const float*)d_in[3];
    const float* Wk = (const float*)d_in[4];
    const float* Wv = (const float*)d_in[5];
    const float* Wo = (const float*)d_in[6];
    const int*  pos = (const int*)d_in[7];

    float* out  = (float*)d_out;        // final; interim: Q (pre-RoPE)
    float* kout = out + BSD;            // fp32 K cache output (post-RoPE)
    float* vout = out + 2*BSD;          // fp32 V cache output

    const size_t D2 = (size_t)D_ * D_;
    const size_t WT_BYTES = D2 * sizeof(bf16);                // 8 MB
    const size_t TB_BYTES = BSD * sizeof(bf16);               // 16 MB bf16 tensor
    const size_t NEED_V7  = 3*WT_BYTES + 3*TB_BYTES;          // 72 MB (obb aliases xb)
    const bool big = ws_size >= WT_BYTES + (size_t)128 * D_ * sizeof(float);

    if (ws_size >= NEED_V7) {
        bf16* wt3 = (bf16*)d_ws;              // 3 transposed weights, 24 MB
        bf16* xb  = wt3 + 3*D2;               // x bf16 (pre-swizzled); obb later
        bf16* kbb = xb + BSD;                 // K bf16 [b,h,s,hd] (pre-swizzled)
        bf16* vbb = kbb + BSD;                // V^T bf16 [b,h,hd,s] (pre-swizzled)
        bf16* obb = xb;                       // attn-out aliases xb (xb dead by then)

        dim3 tg(D_/32, D_/32);
        pack_bf16<<<(int)(BSD/8/256), 256, 0, stream>>>(x, xb);
        transpose_w_s<<<tg, 256, 0, stream>>>(Wq, wt3,        D_, D_);
        transpose_w_s<<<tg, 256, 0, stream>>>(Wk, wt3 + D2,   D_, D_);
        transpose_w_s<<<tg, 256, 0, stream>>>(Wv, wt3 + 2*D2, D_, D_);
        gemm_qkv<<<dim3(M_/128, (3*D_)/128), 256, 0, stream>>>(xb, wt3, out, M_, D_);
        rope_pack_k<<<(B_*S_*H_*8)/256, 256, 0, stream>>>(kout, kbb, cf, sf, pos);
        pack_vt<<<dim3(S_/32, HD_/32, B_*H_), 256, 0, stream>>>(vout, vbb);
        flash_attn_v7<<<dim3(S_/128, B_*H_), 512, 0, stream>>>(out, kbb, vbb, obb,
                                                               cf, sf, pos);
        transpose_w_s<<<tg, 256, 0, stream>>>(Wo, wt3, D_, D_);
        gemm_bb2<<<dim3(M_/128, D_/128), 256, 0, stream>>>(obb, wt3, out, M_, D_, D_);
    } else if (big) {
        bf16*  wt  = (bf16*)d_ws;
        float* cws = (float*)((char*)d_ws + WT_BYTES);
        const size_t crem = ws_size - WT_BYTES;
        dim3 tg(D_/32, D_/32), gg(M_/128, D_/128);
        transpose_w<<<tg, 256, 0, stream>>>(Wq, wt, D_, D_);
        gemm_xw<<<gg, 256, 0, stream>>>(x, wt, out,  M_, D_, D_);
        transpose_w<<<tg, 256, 0, stream>>>(Wk, wt, D_, D_);
        gemm_xw<<<gg, 256, 0, stream>>>(x, wt, kout, M_, D_, D_);
        transpose_w<<<tg, 256, 0, stream>>>(Wv, wt, D_, D_);
        gemm_xw<<<gg, 256, 0, stream>>>(x, wt, vout, M_, D_, D_);
        rope_kernel<<<(2*B_*S_*H_*(HD_/2))/256, 256, 0, stream>>>(out, kout, cf, sf, pos);
        flash_attn<<<dim3(S_/64, B_*H_), 256, 0, stream>>>(out, kout, vout, out);
        transpose_w<<<tg, 256, 0, stream>>>(Wo, wt, D_, D_);
        int R = 128;
        while (R < M_ && (size_t)(2*R) * D_ * sizeof(float) <= crem) R *= 2;
        for (int m0 = 0; m0 < M_; m0 += R) {
            gemm_xw<<<dim3(R/128, D_/128), 256, 0, stream>>>(out + (size_t)m0*D_, wt, cws, R, D_, D_);
            hipMemcpyAsync(out + (size_t)m0*D_, cws, (size_t)R*D_*sizeof(float),
                           hipMemcpyDeviceToDevice, stream);
        }
    } else {
        float* wsb = (float*)d_ws;
        dim3 gg(M_/64, D_/64);
        gemm_f32<<<gg, 256, 0, stream>>>(x, Wq, out,  M_, D_, D_);
        gemm_f32<<<gg, 256, 0, stream>>>(x, Wk, kout, M_, D_, D_);
        gemm_f32<<<gg, 256, 0, stream>>>(x, Wv, vout, M_, D_, D_);
        rope_kernel<<<(2*B_*S_*H_*(HD_/2))/256, 256, 0, stream>>>(out, kout, cf, sf, pos);
        flash_attn<<<dim3(S_/64, B_*H_), 256, 0, stream>>>(out, kout, vout, out);
        int R = 64;
        while (R < M_ && (size_t)(2*R) * D_ * sizeof(float) <= ws_size) R *= 2;
        if ((size_t)R * D_ * sizeof(float) > ws_size) R = 64;
        for (int m0 = 0; m0 < M_; m0 += R) {
            gemm_f32<<<dim3(R/64, D_/64), 256, 0, stream>>>(out + (size_t)m0*D_, Wo, wsb, R, D_, D_);
            hipMemcpyAsync(out + (size_t)m0*D_, wsb, (size_t)R*D_*sizeof(float),
                           hipMemcpyDeviceToDevice, stream);
        }
    }
}